// Round 5
// baseline (3054.982 us; speedup 1.0000x reference)
//
#include <hip/hip_runtime.h>
#include <stdint.h>
#include <stddef.h>
#include <math.h>

// ContextSNN round 5: i8 MFMA, 3 digit planes, balanced split-K z=8 with
// in-kernel plane-fold (exact i32 per plane segment -> fp32 scaled).
// T=50, B=256, IN=1536, H1=H2=4096, OUT=64. LIF beta=0.9, thr=1, subtract.

#define T_STEPS 50
#define BATCH   256
#define N_H     4096
#define DEN     8355711   // 127*65536 + 127*256 + 127

typedef unsigned short u16;
typedef __attribute__((ext_vector_type(4))) int i32x4;
typedef __attribute__((ext_vector_type(4))) float f32x4;

#define GLL16(gp, lp) __builtin_amdgcn_global_load_lds( \
    (const __attribute__((address_space(1))) void*)(gp), \
    (__attribute__((address_space(3))) void*)(lp), 16, 0, 0)

// ---------------------------------------------------------------------------
// prep
// ---------------------------------------------------------------------------
__global__ __launch_bounds__(256) void zero_ws(float4* __restrict__ p) {
    p[(size_t)blockIdx.x * 256 + threadIdx.x] = make_float4(0.f, 0.f, 0.f, 0.f);
}

__device__ inline void digits3(float w, float inv_s, int& h, int& m, int& l) {
    int V = (int)rintf(w * inv_s);
    V = min(max(V, -DEN), DEN);
    l = ((V + 128) & 255) - 128;
    const int V2 = (V - l) >> 8;
    m = ((V2 + 128) & 255) - 128;
    h = (V2 - m) >> 8;
}

__global__ __launch_bounds__(256)
void split3_i8(const float4* __restrict__ W, char* __restrict__ P,
               size_t plane_elems, float inv_s)
{
    const size_t i = (size_t)blockIdx.x * 256 + threadIdx.x;
    const float4 w = W[i];
    int h0,m0,l0,h1,m1,l1,h2,m2,l2,h3,m3,l3;
    digits3(w.x, inv_s, h0, m0, l0);
    digits3(w.y, inv_s, h1, m1, l1);
    digits3(w.z, inv_s, h2, m2, l2);
    digits3(w.w, inv_s, h3, m3, l3);
    const uint32_t ph = (uint32_t)(uint8_t)h0 | ((uint32_t)(uint8_t)h1 << 8) |
                        ((uint32_t)(uint8_t)h2 << 16) | ((uint32_t)(uint8_t)h3 << 24);
    const uint32_t pm = (uint32_t)(uint8_t)m0 | ((uint32_t)(uint8_t)m1 << 8) |
                        ((uint32_t)(uint8_t)m2 << 16) | ((uint32_t)(uint8_t)m3 << 24);
    const uint32_t pl = (uint32_t)(uint8_t)l0 | ((uint32_t)(uint8_t)l1 << 8) |
                        ((uint32_t)(uint8_t)l2 << 16) | ((uint32_t)(uint8_t)l3 << 24);
    *(uint32_t*)&P[4 * i]                   = ph;
    *(uint32_t*)&P[plane_elems + 4 * i]     = pm;
    *(uint32_t*)&P[2 * plane_elems + 4 * i] = pl;
}

__global__ __launch_bounds__(256)
void xcvt_i8(const float4* __restrict__ in, uint32_t* __restrict__ out) {
    const size_t i = (size_t)blockIdx.x * 256 + threadIdx.x;
    const float4 v = in[i];
    out[i] = (uint32_t)(v.x > 0.5f) | ((uint32_t)(v.y > 0.5f) << 8) |
             ((uint32_t)(v.z > 0.5f) << 16) | ((uint32_t)(v.w > 0.5f) << 24);
}

// ---------------------------------------------------------------------------
// i8 MFMA GEMM, balanced split-K: grid (32,2,8) = 512 blocks = 2/CU.
// Block 128x128, 4 waves 64x64, BK=64. z covers flat (plane,k) range of
// length F = 3K/8; on plane boundary the i32 acc is folded into f32 acc
// with scale s_base * 256^(2-p)  (i32 segment sums < 2^24 -> fold exact).
// ---------------------------------------------------------------------------
template<int K, int F>
__global__ __launch_bounds__(256, 2)
void gemm_i8(const char* __restrict__ A, const char* __restrict__ Wp,
             float* __restrict__ part, float s_base)
{
    __shared__ char As[128 * 64];
    __shared__ char Bs[128 * 64];

    const int tid  = threadIdx.x;
    const int wave = tid >> 6, lane = tid & 63;
    const int wm = wave >> 1, wn = wave & 1;

    const int cbase = blockIdx.x * 128;
    const int abase = blockIdx.y * 128;
    const int z = blockIdx.z;          // 0..7

    int p = (z * F) / K;
    int k = z * F - p * K;

    i32x4 acc[4][4];
    f32x4 facc[4][4];
#pragma unroll
    for (int i = 0; i < 4; ++i)
#pragma unroll
        for (int j = 0; j < 4; ++j) { acc[i][j] = (i32x4)(0); facc[i][j] = (f32x4)(0.f); }

    const int soff0 = wave * 2048 + lane * 16;
    const int soff1 = soff0 + 1024;
    const int r0 = soff0 >> 6, kb0 = soff0 & 63;
    const int r1 = soff1 >> 6, kb1 = soff1 & 63;

    const size_t aoff0 = (size_t)(abase + r0) * K + kb0;
    const size_t aoff1 = (size_t)(abase + r1) * K + kb1;
    const size_t boff0 = (size_t)(cbase + r0) * K + kb0;
    const size_t boff1 = (size_t)(cbase + r1) * K + kb1;

    char* ldsA0 = As + wave * 2048;
    char* ldsA1 = ldsA0 + 1024;
    char* ldsB0 = Bs + wave * 2048;
    char* ldsB1 = ldsB0 + 1024;

    const int rlo = lane & 15, rhi = lane >> 4;
    const char* pAf = As + (wm * 64 + rlo) * 64 + rhi * 16;
    const char* pBf = Bs + (wn * 64 + rlo) * 64 + rhi * 16;

    for (int f = 0; f < F; f += 64) {
        const char* ak = A + k;
        const char* bk = Wp + (size_t)p * N_H * K + k;
        __syncthreads();
        GLL16(ak + aoff0, ldsA0);
        GLL16(ak + aoff1, ldsA1);
        GLL16(bk + boff0, ldsB0);
        GLL16(bk + boff1, ldsB1);
        __syncthreads();

        i32x4 av[4], bv[4];
#pragma unroll
        for (int i = 0; i < 4; ++i) av[i] = *(const i32x4*)(pAf + i * 1024);
#pragma unroll
        for (int j = 0; j < 4; ++j) bv[j] = *(const i32x4*)(pBf + j * 1024);
#pragma unroll
        for (int i = 0; i < 4; ++i)
#pragma unroll
            for (int j = 0; j < 4; ++j)
                acc[i][j] = __builtin_amdgcn_mfma_i32_16x16x64_i8(
                    av[i], bv[j], acc[i][j], 0, 0, 0);

        k += 64;
        if (k >= K) {   // plane boundary: fold exact i32 segment into f32
            const float sc = s_base * (float)(65536 >> (8 * p));
#pragma unroll
            for (int i = 0; i < 4; ++i)
#pragma unroll
                for (int j = 0; j < 4; ++j) {
#pragma unroll
                    for (int r = 0; r < 4; ++r)
                        facc[i][j][r] += sc * (float)acc[i][j][r];
                    acc[i][j] = (i32x4)(0);
                }
            k = 0; ++p;
        }
    }
    {   // final fold (sc=0 when p>2, harmless)
        const float sc = (p <= 2) ? s_base * (float)(65536 >> (8 * p)) : 0.f;
#pragma unroll
        for (int i = 0; i < 4; ++i)
#pragma unroll
            for (int j = 0; j < 4; ++j)
#pragma unroll
                for (int r = 0; r < 4; ++r)
                    facc[i][j][r] += sc * (float)acc[i][j][r];
    }

    float* pout = part + (size_t)z * (BATCH * N_H);
    const int orow = abase + wm * 64 + rhi * 4;
    const int ocol = cbase + wn * 64 + rlo;
#pragma unroll
    for (int i = 0; i < 4; ++i)
#pragma unroll
        for (int j = 0; j < 4; ++j)
#pragma unroll
            for (int r = 0; r < 4; ++r)
                pout[(size_t)(orow + i * 16 + r) * N_H + ocol + j * 16] = facc[i][j][r];
}

// ---------------------------------------------------------------------------
// layer-3 i8 GEMM (round-4, proven): A = s2 i8 [12800][4096], W3p[3][64][4096].
// ---------------------------------------------------------------------------
__global__ __launch_bounds__(256, 2)
void gemm3_i8(const char* __restrict__ A, const char* __restrict__ W3p,
              float* __restrict__ part3, float s_base)
{
    __shared__ char As[128 * 64];
    __shared__ char Bs[64 * 64];

    const int tid  = threadIdx.x;
    const int wave = tid >> 6, lane = tid & 63;
    const int wm = wave >> 1, wn = wave & 1;

    const int rowbase = blockIdx.x * 128;
    const int z = blockIdx.y;
    const int p = z >> 1;
    const int kstart = (z & 1) * 2048;

    i32x4 acc[4][2];
#pragma unroll
    for (int i = 0; i < 4; ++i)
#pragma unroll
        for (int j = 0; j < 2; ++j) acc[i][j] = (i32x4)(0);

    const int soff0 = wave * 2048 + lane * 16;
    const int soff1 = soff0 + 1024;
    const int r0 = soff0 >> 6, kb0 = soff0 & 63;
    const int r1 = soff1 >> 6, kb1 = soff1 & 63;
    const int soffB = tid * 16;
    const int rB = soffB >> 6, kbB = soffB & 63;

    const size_t aoff0 = (size_t)(rowbase + r0) * 4096 + kb0;
    const size_t aoff1 = (size_t)(rowbase + r1) * 4096 + kb1;
    const size_t boff  = (size_t)rB * 4096 + kbB;

    const char* Bp = W3p + (size_t)p * 64 * 4096;

    char* ldsA0 = As + wave * 2048;
    char* ldsA1 = ldsA0 + 1024;
    char* ldsB  = Bs + wave * 1024;

    const int rlo = lane & 15, rhi = lane >> 4;
    const char* pAf = As + (wm * 64 + rlo) * 64 + rhi * 16;
    const char* pBf = Bs + (wn * 32 + rlo) * 64 + rhi * 16;

    for (int it = 0; it < 32; ++it) {
        const int k = kstart + it * 64;
        __syncthreads();
        GLL16(A + k + aoff0, ldsA0);
        GLL16(A + k + aoff1, ldsA1);
        GLL16(Bp + k + boff, ldsB);
        __syncthreads();

        i32x4 av[4], bv[2];
#pragma unroll
        for (int i = 0; i < 4; ++i) av[i] = *(const i32x4*)(pAf + i * 1024);
#pragma unroll
        for (int j = 0; j < 2; ++j) bv[j] = *(const i32x4*)(pBf + j * 1024);
#pragma unroll
        for (int i = 0; i < 4; ++i)
#pragma unroll
            for (int j = 0; j < 2; ++j)
                acc[i][j] = __builtin_amdgcn_mfma_i32_16x16x64_i8(
                    av[i], bv[j], acc[i][j], 0, 0, 0);
    }

    const float sc = s_base * (float)(65536 >> (8 * p));
    float* pout = part3 + (size_t)z * (12800 * 64);
    const int orow = rowbase + wm * 64 + rhi * 4;
    const int ocol = wn * 32 + rlo;
#pragma unroll
    for (int i = 0; i < 4; ++i)
#pragma unroll
        for (int j = 0; j < 2; ++j)
#pragma unroll
            for (int r = 0; r < 4; ++r)
                pout[(size_t)(orow + i * 16 + r) * 64 + ocol + j * 16] =
                    (float)acc[i][j][r] * sc;
}

// ---------------------------------------------------------------------------
// reduce 8 partials + bias, LIF, float4-vectorized. One thread per 4 elems.
// ---------------------------------------------------------------------------
__global__ __launch_bounds__(256)
void reduce_lif(const float* __restrict__ part, const float* __restrict__ bias,
                float* __restrict__ mem, char* __restrict__ sout)
{
    const int i4 = blockIdx.x * 256 + threadIdx.x;   // 0 .. 262143
    const size_t base = (size_t)i4 * 4;
    const int col = (int)(base & (N_H - 1));
    float4 cur = *(const float4*)&bias[col];
#pragma unroll
    for (int g = 0; g < 8; ++g) {
        const float4 pv = *(const float4*)&part[(size_t)g * (BATCH * N_H) + base];
        cur.x += pv.x; cur.y += pv.y; cur.z += pv.z; cur.w += pv.w;
    }
    const float4 mp = *(const float4*)&mem[base];
    float4 mn;
    mn.x = 0.9f * mp.x + cur.x - ((mp.x > 1.0f) ? 1.0f : 0.0f);
    mn.y = 0.9f * mp.y + cur.y - ((mp.y > 1.0f) ? 1.0f : 0.0f);
    mn.z = 0.9f * mp.z + cur.z - ((mp.z > 1.0f) ? 1.0f : 0.0f);
    mn.w = 0.9f * mp.w + cur.w - ((mp.w > 1.0f) ? 1.0f : 0.0f);
    *(float4*)&mem[base] = mn;
    const uint32_t sp = (uint32_t)(mn.x > 1.0f) | ((uint32_t)(mn.y > 1.0f) << 8) |
                        ((uint32_t)(mn.z > 1.0f) << 16) | ((uint32_t)(mn.w > 1.0f) << 24);
    *(uint32_t*)&sout[base] = sp;
}

// combine 6 group partials + bias, sequential LIF over t
template<int NG>
__global__ __launch_bounds__(256)
void lif3_scan(const float* __restrict__ part, const float* __restrict__ b3,
               float* __restrict__ out)
{
    const int g = blockIdx.x * 256 + threadIdx.x;
    const int j = g & 63;
    const int b = g >> 6;
    const float bj = b3[j];
    float m = 0.f, accum = 0.f;
    for (int t = 0; t < T_STEPS; ++t) {
        const size_t row = (size_t)t * 256 + b;
        float cur = bj;
#pragma unroll
        for (int q = 0; q < NG; ++q)
            cur += part[(size_t)q * (12800 * 64) + row * 64 + j];
        const float reset = (m > 1.0f) ? 1.0f : 0.0f;
        m = 0.9f * m + cur - reset;
        accum += (m > 1.0f) ? 1.0f : 0.0f;
    }
    out[g] = accum;
}

// ---------------------------------------------------------------------------
// fp32 fallback path (round 1) — used only if ws_size too small
// ---------------------------------------------------------------------------
template<int K, bool PACK_BITS>
__global__ __launch_bounds__(512)
void gemm_lif(const float* __restrict__ A, const float* __restrict__ W,
              const float* __restrict__ bias, float* __restrict__ mem,
              float* __restrict__ s_f32, uint32_t* __restrict__ s_bits)
{
    __shared__ float Asf[32][68];
    __shared__ float Wsf[32][68];
    __shared__ uint8_t us[64][64];

    const int tid = threadIdx.x;
    const int abase = blockIdx.y * 64;
    const int cbase = blockIdx.x * 64;
    const int tx = tid & 15;
    const int ty = tid >> 4;

    float acc[2][4];
#pragma unroll
    for (int i = 0; i < 2; ++i)
#pragma unroll
        for (int j = 0; j < 4; ++j) acc[i][j] = 0.f;

    const int lrow = tid >> 3;
    const int lg = tid & 7;

    for (int k0 = 0; k0 < K; k0 += 32) {
        const float4 av = *(const float4*)&A[(size_t)(abase + lrow) * K + k0 + lg * 4];
        const float4 wv = *(const float4*)&W[(size_t)(cbase + lrow) * K + k0 + lg * 4];
        __syncthreads();
        Asf[lg * 4 + 0][lrow] = av.x; Asf[lg * 4 + 1][lrow] = av.y;
        Asf[lg * 4 + 2][lrow] = av.z; Asf[lg * 4 + 3][lrow] = av.w;
        Wsf[lg * 4 + 0][lrow] = wv.x; Wsf[lg * 4 + 1][lrow] = wv.y;
        Wsf[lg * 4 + 2][lrow] = wv.z; Wsf[lg * 4 + 3][lrow] = wv.w;
        __syncthreads();
#pragma unroll
        for (int kk = 0; kk < 32; ++kk) {
            const float2 a2 = *(const float2*)&Asf[kk][ty * 2];
            const float4 b4 = *(const float4*)&Wsf[kk][tx * 4];
            acc[0][0] += a2.x * b4.x; acc[0][1] += a2.x * b4.y;
            acc[0][2] += a2.x * b4.z; acc[0][3] += a2.x * b4.w;
            acc[1][0] += a2.y * b4.x; acc[1][1] += a2.y * b4.y;
            acc[1][2] += a2.y * b4.z; acc[1][3] += a2.y * b4.w;
        }
    }

    const int r0 = abase + ty * 2;
    const int c0loc = tx * 4;
    const int c0 = cbase + c0loc;
    const float4 bv = *(const float4*)&bias[c0];

#pragma unroll
    for (int i = 0; i < 2; ++i) {
        const size_t off = (size_t)(r0 + i) * N_H + c0;
        const float4 mp = *(const float4*)&mem[off];
        float4 mn, sp;
        { float cur = acc[i][0] + bv.x;
          mn.x = 0.9f * mp.x + cur - ((mp.x > 1.0f) ? 1.0f : 0.0f);
          sp.x = (mn.x > 1.0f) ? 1.0f : 0.0f; }
        { float cur = acc[i][1] + bv.y;
          mn.y = 0.9f * mp.y + cur - ((mp.y > 1.0f) ? 1.0f : 0.0f);
          sp.y = (mn.y > 1.0f) ? 1.0f : 0.0f; }
        { float cur = acc[i][2] + bv.z;
          mn.z = 0.9f * mp.z + cur - ((mp.z > 1.0f) ? 1.0f : 0.0f);
          sp.z = (mn.z > 1.0f) ? 1.0f : 0.0f; }
        { float cur = acc[i][3] + bv.w;
          mn.w = 0.9f * mp.w + cur - ((mp.w > 1.0f) ? 1.0f : 0.0f);
          sp.w = (mn.w > 1.0f) ? 1.0f : 0.0f; }
        *(float4*)&mem[off] = mn;
        if constexpr (!PACK_BITS) {
            *(float4*)&s_f32[off] = sp;
        } else {
            us[ty * 2 + i][c0loc + 0] = (uint8_t)sp.x;
            us[ty * 2 + i][c0loc + 1] = (uint8_t)sp.y;
            us[ty * 2 + i][c0loc + 2] = (uint8_t)sp.z;
            us[ty * 2 + i][c0loc + 3] = (uint8_t)sp.w;
        }
    }

    if constexpr (PACK_BITS) {
        __syncthreads();
        if (tid < 128) {
            const int r = tid >> 1;
            const int w = tid & 1;
            uint32_t bits = 0;
#pragma unroll
            for (int b = 0; b < 32; ++b)
                bits |= ((uint32_t)us[r][w * 32 + b]) << b;
            s_bits[(size_t)(abase + r) * 128 + (cbase >> 5) + w] = bits;
        }
    }
}

__global__ __launch_bounds__(256)
void gemm3_bits(const uint32_t* __restrict__ s_bits, const float* __restrict__ W3,
                float* __restrict__ part)
{
    __shared__ float Asf[32][68];
    __shared__ float Wsf[32][68];

    const int tid = threadIdx.x;
    const int rowbase = blockIdx.x * 64;
    const int ks = blockIdx.y;
    const int tx = tid & 15;
    const int ty = tid >> 4;

    float acc[4][4];
#pragma unroll
    for (int i = 0; i < 4; ++i)
#pragma unroll
        for (int j = 0; j < 4; ++j) acc[i][j] = 0.f;

    const int r  = tid & 63;
    const int q  = tid >> 6;
    const int wr = tid >> 3;
    const int wg = tid & 7;

    for (int c = 0; c < 32; ++c) {
        const int k0 = ks * 1024 + c * 32;
        const uint32_t word = s_bits[(size_t)(rowbase + r) * 128 + (k0 >> 5)];
        const float4 wv0 = *(const float4*)&W3[(size_t)wr * 4096 + k0 + wg * 4];
        const float4 wv1 = *(const float4*)&W3[(size_t)(wr + 32) * 4096 + k0 + wg * 4];
        __syncthreads();
#pragma unroll
        for (int u = 0; u < 8; ++u)
            Asf[q * 8 + u][r] = (float)((word >> (q * 8 + u)) & 1u);
        Wsf[wg * 4 + 0][wr] = wv0.x;
        Wsf[wg * 4 + 1][wr] = wv0.y;
        Wsf[wg * 4 + 2][wr] = wv0.z;
        Wsf[wg * 4 + 3][wr] = wv0.w;
        Wsf[wg * 4 + 0][wr + 32] = wv1.x;
        Wsf[wg * 4 + 1][wr + 32] = wv1.y;
        Wsf[wg * 4 + 2][wr + 32] = wv1.z;
        Wsf[wg * 4 + 3][wr + 32] = wv1.w;
        __syncthreads();
#pragma unroll
        for (int kk = 0; kk < 32; ++kk) {
            const float4 a4 = *(const float4*)&Asf[kk][ty * 4];
            const float4 b4 = *(const float4*)&Wsf[kk][tx * 4];
            acc[0][0] += a4.x * b4.x; acc[0][1] += a4.x * b4.y;
            acc[0][2] += a4.x * b4.z; acc[0][3] += a4.x * b4.w;
            acc[1][0] += a4.y * b4.x; acc[1][1] += a4.y * b4.y;
            acc[1][2] += a4.y * b4.z; acc[1][3] += a4.y * b4.w;
            acc[2][0] += a4.z * b4.x; acc[2][1] += a4.z * b4.y;
            acc[2][2] += a4.z * b4.z; acc[2][3] += a4.z * b4.w;
            acc[3][0] += a4.w * b4.x; acc[3][1] += a4.w * b4.y;
            acc[3][2] += a4.w * b4.z; acc[3][3] += a4.w * b4.w;
        }
    }
#pragma unroll
    for (int i = 0; i < 4; ++i) {
        float4 v = make_float4(acc[i][0], acc[i][1], acc[i][2], acc[i][3]);
        *(float4*)&part[((size_t)ks * 12800 + rowbase + ty * 4 + i) * 64 + tx * 4] = v;
    }
}

// ---------------------------------------------------------------------------
extern "C" void kernel_launch(void* const* d_in, const int* in_sizes, int n_in,
                              void* d_out, int out_size, void* d_ws, size_t ws_size,
                              hipStream_t stream)
{
    const float* x  = (const float*)d_in[0];
    const float* W1 = (const float*)d_in[1];
    const float* b1 = (const float*)d_in[2];
    const float* W2 = (const float*)d_in[3];
    const float* b2 = (const float*)d_in[4];
    const float* W3 = (const float*)d_in[5];
    const float* b3 = (const float*)d_in[6];

    char* ws = (char*)d_ws;

    const size_t oW1p  = 0;              // 18,874,368
    const size_t oW2p  = 18874368;       // 50,331,648
    const size_t oW3p  = 69206016;       //    786,432
    const size_t oXi8  = 69992448;       // 19,660,800
    const size_t oS1   = 89653248;       //  1,048,576
    const size_t oS2   = 90701824;       // 52,428,800
    const size_t oM1   = 143130624;      //  4,194,304
    const size_t oM2   = 147324928;      //  4,194,304
    const size_t oPart = 151519232;      // 33,554,432 (8 x 4 MB; part3 aliases)
    const size_t NEED  = 185073664;

    const double bnd1 = 1.0 / sqrt(1536.0);
    const double bnd2 = 1.0 / 64.0;
    const double bnd3 = 1.0 / 64.0;
    const float inv1 = (float)((double)DEN / bnd1), sb1 = (float)(bnd1 / (double)DEN);
    const float inv2 = (float)((double)DEN / bnd2), sb2 = (float)(bnd2 / (double)DEN);
    const float inv3 = (float)((double)DEN / bnd3), sb3 = (float)(bnd3 / (double)DEN);

    if (ws_size >= NEED) {
        char*  W1p  = ws + oW1p;
        char*  W2p  = ws + oW2p;
        char*  W3p  = ws + oW3p;
        char*  xi8  = ws + oXi8;
        char*  s1   = ws + oS1;
        char*  s2   = ws + oS2;
        float* m1   = (float*)(ws + oM1);
        float* m2   = (float*)(ws + oM2);
        float* part = (float*)(ws + oPart);
        float* part3 = part;

        split3_i8<<<6144, 256, 0, stream>>>((const float4*)W1, W1p,
                                            (size_t)4096 * 1536, inv1);
        split3_i8<<<16384, 256, 0, stream>>>((const float4*)W2, W2p,
                                             (size_t)4096 * 4096, inv2);
        split3_i8<<<256, 256, 0, stream>>>((const float4*)W3, W3p,
                                           (size_t)64 * 4096, inv3);
        xcvt_i8<<<19200, 256, 0, stream>>>((const float4*)x, (uint32_t*)xi8);
        zero_ws<<<2048, 256, 0, stream>>>((float4*)m1);   // m1 + m2 contiguous

        for (int t = 0; t < T_STEPS; ++t) {
            gemm_i8<1536, 576><<<dim3(32, 2, 8), 256, 0, stream>>>(
                xi8 + (size_t)t * BATCH * 1536, W1p, part, sb1);
            reduce_lif<<<1024, 256, 0, stream>>>(part, b1, m1, s1);
            gemm_i8<4096, 1536><<<dim3(32, 2, 8), 256, 0, stream>>>(
                s1, W2p, part, sb2);
            reduce_lif<<<1024, 256, 0, stream>>>(part, b2, m2,
                                                 s2 + (size_t)t * BATCH * N_H);
        }
        gemm3_i8<<<dim3(100, 6), 256, 0, stream>>>(s2, W3p, part3, sb3);
        lif3_scan<6><<<64, 256, 0, stream>>>(part3, b3, (float*)d_out);
    } else {
        float*    m1     = (float*)(ws);
        float*    m2     = (float*)(ws + (size_t)4 * 1024 * 1024);
        float*    s1     = (float*)(ws + (size_t)8 * 1024 * 1024);
        uint32_t* s2bits = (uint32_t*)(ws + (size_t)12 * 1024 * 1024);
        float*    part   = (float*)(ws + (size_t)20 * 1024 * 1024);

        zero_ws<<<2048, 256, 0, stream>>>((float4*)m1);
        for (int t = 0; t < T_STEPS; ++t) {
            gemm_lif<1536, false><<<dim3(64, 4), 512, 0, stream>>>(
                x + (size_t)t * BATCH * 1536, W1, b1, m1, s1, nullptr);
            gemm_lif<4096, true><<<dim3(64, 4), 512, 0, stream>>>(
                s1, W2, b2, m2, nullptr, s2bits + (size_t)t * BATCH * 128);
        }
        gemm3_bits<<<dim3(200, 4), 256, 0, stream>>>(s2bits, W3, part);
        lif3_scan<4><<<64, 256, 0, stream>>>(part, b3, (float*)d_out);
    }
}

// Round 6
// 2278.312 us; speedup vs baseline: 1.3409x; 1.3409x over previous
//
#include <hip/hip_runtime.h>
#include <stdint.h>
#include <stddef.h>
#include <math.h>

// ContextSNN round 6: i8 MFMA, 3 digit planes.
//  - Layer 1 batched over time (2 chunks x 25 steps, no split-K, no partials)
//  - Layer 2 = r4-proven z=6 plane-aligned split-K + vectorized reduce
//  - reduce2(t) fused with lif1(t+1)
// T=50, B=256, IN=1536, H1=H2=4096, OUT=64. LIF beta=0.9, thr=1, subtract.

#define T_STEPS 50
#define BATCH   256
#define N_H     4096
#define DEN     8355711   // 127*65536 + 127*256 + 127

typedef unsigned short u16;
typedef __attribute__((ext_vector_type(4))) int i32x4;
typedef __attribute__((ext_vector_type(4))) float f32x4;

#define GLL16(gp, lp) __builtin_amdgcn_global_load_lds( \
    (const __attribute__((address_space(1))) void*)(gp), \
    (__attribute__((address_space(3))) void*)(lp), 16, 0, 0)

// ---------------------------------------------------------------------------
// prep
// ---------------------------------------------------------------------------
__global__ __launch_bounds__(256) void zero_ws(float4* __restrict__ p) {
    p[(size_t)blockIdx.x * 256 + threadIdx.x] = make_float4(0.f, 0.f, 0.f, 0.f);
}

__device__ inline void digits3(float w, float inv_s, int& h, int& m, int& l) {
    int V = (int)rintf(w * inv_s);
    V = min(max(V, -DEN), DEN);
    l = ((V + 128) & 255) - 128;
    const int V2 = (V - l) >> 8;
    m = ((V2 + 128) & 255) - 128;
    h = (V2 - m) >> 8;
}

__global__ __launch_bounds__(256)
void split3_i8(const float4* __restrict__ W, char* __restrict__ P,
               size_t plane_elems, float inv_s)
{
    const size_t i = (size_t)blockIdx.x * 256 + threadIdx.x;
    const float4 w = W[i];
    int h0,m0,l0,h1,m1,l1,h2,m2,l2,h3,m3,l3;
    digits3(w.x, inv_s, h0, m0, l0);
    digits3(w.y, inv_s, h1, m1, l1);
    digits3(w.z, inv_s, h2, m2, l2);
    digits3(w.w, inv_s, h3, m3, l3);
    const uint32_t ph = (uint32_t)(uint8_t)h0 | ((uint32_t)(uint8_t)h1 << 8) |
                        ((uint32_t)(uint8_t)h2 << 16) | ((uint32_t)(uint8_t)h3 << 24);
    const uint32_t pm = (uint32_t)(uint8_t)m0 | ((uint32_t)(uint8_t)m1 << 8) |
                        ((uint32_t)(uint8_t)m2 << 16) | ((uint32_t)(uint8_t)m3 << 24);
    const uint32_t pl = (uint32_t)(uint8_t)l0 | ((uint32_t)(uint8_t)l1 << 8) |
                        ((uint32_t)(uint8_t)l2 << 16) | ((uint32_t)(uint8_t)l3 << 24);
    *(uint32_t*)&P[4 * i]                   = ph;
    *(uint32_t*)&P[plane_elems + 4 * i]     = pm;
    *(uint32_t*)&P[2 * plane_elems + 4 * i] = pl;
}

__global__ __launch_bounds__(256)
void xcvt_i8(const float4* __restrict__ in, uint32_t* __restrict__ out) {
    const size_t i = (size_t)blockIdx.x * 256 + threadIdx.x;
    const float4 v = in[i];
    out[i] = (uint32_t)(v.x > 0.5f) | ((uint32_t)(v.y > 0.5f) << 8) |
             ((uint32_t)(v.z > 0.5f) << 16) | ((uint32_t)(v.w > 0.5f) << 24);
}

// ---------------------------------------------------------------------------
// Layer-1 batched GEMM: A[6400][1536] (25 steps) x W1p[3][4096][1536]^T.
// Block 128x128, 4 waves 64x64, BK=64, full flat-K=4608 with plane-fold.
// Writes raw fp32 currents (bias added in lif1). Grid (32, 50), no split-K.
// ---------------------------------------------------------------------------
__global__ __launch_bounds__(256, 2)
void gemm1_full(const char* __restrict__ A, const char* __restrict__ Wp,
                float* __restrict__ cur, float s_base)
{
    const int K = 1536, F = 4608;
    __shared__ char As[128 * 64];
    __shared__ char Bs[128 * 64];

    const int tid  = threadIdx.x;
    const int wave = tid >> 6, lane = tid & 63;
    const int wm = wave >> 1, wn = wave & 1;

    const int cbase = blockIdx.x * 128;
    const int abase = blockIdx.y * 128;

    int p = 0, k = 0;

    i32x4 acc[4][4];
    f32x4 facc[4][4];
#pragma unroll
    for (int i = 0; i < 4; ++i)
#pragma unroll
        for (int j = 0; j < 4; ++j) { acc[i][j] = (i32x4)(0); facc[i][j] = (f32x4)(0.f); }

    const int soff0 = wave * 2048 + lane * 16;
    const int soff1 = soff0 + 1024;
    const int r0 = soff0 >> 6, kb0 = soff0 & 63;
    const int r1 = soff1 >> 6, kb1 = soff1 & 63;

    const size_t aoff0 = (size_t)(abase + r0) * K + kb0;
    const size_t aoff1 = (size_t)(abase + r1) * K + kb1;
    const size_t boff0 = (size_t)(cbase + r0) * K + kb0;
    const size_t boff1 = (size_t)(cbase + r1) * K + kb1;

    char* ldsA0 = As + wave * 2048;
    char* ldsA1 = ldsA0 + 1024;
    char* ldsB0 = Bs + wave * 2048;
    char* ldsB1 = ldsB0 + 1024;

    const int rlo = lane & 15, rhi = lane >> 4;
    const char* pAf = As + (wm * 64 + rlo) * 64 + rhi * 16;
    const char* pBf = Bs + (wn * 64 + rlo) * 64 + rhi * 16;

    for (int f = 0; f < F; f += 64) {
        const char* ak = A + k;
        const char* bk = Wp + (size_t)p * N_H * K + k;
        __syncthreads();
        GLL16(ak + aoff0, ldsA0);
        GLL16(ak + aoff1, ldsA1);
        GLL16(bk + boff0, ldsB0);
        GLL16(bk + boff1, ldsB1);
        __syncthreads();

        i32x4 av[4], bv[4];
#pragma unroll
        for (int i = 0; i < 4; ++i) av[i] = *(const i32x4*)(pAf + i * 1024);
#pragma unroll
        for (int j = 0; j < 4; ++j) bv[j] = *(const i32x4*)(pBf + j * 1024);
#pragma unroll
        for (int i = 0; i < 4; ++i)
#pragma unroll
            for (int j = 0; j < 4; ++j)
                acc[i][j] = __builtin_amdgcn_mfma_i32_16x16x64_i8(
                    av[i], bv[j], acc[i][j], 0, 0, 0);

        k += 64;
        if (k >= K) {   // plane boundary: fold exact i32 segment into f32
            const float sc = s_base * (float)(65536 >> (8 * p));
#pragma unroll
            for (int i = 0; i < 4; ++i)
#pragma unroll
                for (int j = 0; j < 4; ++j) {
#pragma unroll
                    for (int r = 0; r < 4; ++r)
                        facc[i][j][r] += sc * (float)acc[i][j][r];
                    acc[i][j] = (i32x4)(0);
                }
            k = 0; ++p;
        }
    }

    const int orow = abase + wm * 64 + rhi * 4;
    const int ocol = cbase + wn * 64 + rlo;
#pragma unroll
    for (int i = 0; i < 4; ++i)
#pragma unroll
        for (int j = 0; j < 4; ++j)
#pragma unroll
            for (int r = 0; r < 4; ++r)
                cur[(size_t)(orow + i * 16 + r) * N_H + ocol + j * 16] = facc[i][j][r];
}

// ---------------------------------------------------------------------------
// Layer-2 GEMM (r4-proven): z = plane*2 + K-half, plane-aligned, no fold.
// Block 128x128, 4 waves 64x64, BK=64. Grid (32, 2, 6).
// ---------------------------------------------------------------------------
template<int K>
__global__ __launch_bounds__(256, 2)
void gemm_i8(const char* __restrict__ A, const char* __restrict__ Wp,
             float* __restrict__ part, float s_base)
{
    __shared__ char As[128 * 64];
    __shared__ char Bs[128 * 64];

    const int tid  = threadIdx.x;
    const int wave = tid >> 6, lane = tid & 63;
    const int wm = wave >> 1, wn = wave & 1;

    const int cbase = blockIdx.x * 128;
    const int abase = blockIdx.y * 128;
    const int z = blockIdx.z;          // 0..5
    const int p = z >> 1;
    const int kstart = (z & 1) * (K / 2);

    i32x4 acc[4][4];
#pragma unroll
    for (int i = 0; i < 4; ++i)
#pragma unroll
        for (int j = 0; j < 4; ++j) acc[i][j] = (i32x4)(0);

    const int soff0 = wave * 2048 + lane * 16;
    const int soff1 = soff0 + 1024;
    const int r0 = soff0 >> 6, kb0 = soff0 & 63;
    const int r1 = soff1 >> 6, kb1 = soff1 & 63;

    const size_t aoff0 = (size_t)(abase + r0) * K + kb0;
    const size_t aoff1 = (size_t)(abase + r1) * K + kb1;
    const size_t boff0 = (size_t)(cbase + r0) * K + kb0;
    const size_t boff1 = (size_t)(cbase + r1) * K + kb1;

    const char* Bp = Wp + (size_t)p * N_H * K;

    char* ldsA0 = As + wave * 2048;
    char* ldsA1 = ldsA0 + 1024;
    char* ldsB0 = Bs + wave * 2048;
    char* ldsB1 = ldsB0 + 1024;

    const int rlo = lane & 15, rhi = lane >> 4;
    const char* pAf = As + (wm * 64 + rlo) * 64 + rhi * 16;
    const char* pBf = Bs + (wn * 64 + rlo) * 64 + rhi * 16;

#pragma unroll 2
    for (int it = 0; it < K / 128; ++it) {
        const int k = kstart + it * 64;
        const char* ak = A + k;
        const char* bk = Bp + k;
        __syncthreads();
        GLL16(ak + aoff0, ldsA0);
        GLL16(ak + aoff1, ldsA1);
        GLL16(bk + boff0, ldsB0);
        GLL16(bk + boff1, ldsB1);
        __syncthreads();

        i32x4 av[4], bv[4];
#pragma unroll
        for (int i = 0; i < 4; ++i) av[i] = *(const i32x4*)(pAf + i * 1024);
#pragma unroll
        for (int j = 0; j < 4; ++j) bv[j] = *(const i32x4*)(pBf + j * 1024);
#pragma unroll
        for (int i = 0; i < 4; ++i)
#pragma unroll
            for (int j = 0; j < 4; ++j)
                acc[i][j] = __builtin_amdgcn_mfma_i32_16x16x64_i8(
                    av[i], bv[j], acc[i][j], 0, 0, 0);
    }

    const float sc = s_base * (float)(65536 >> (8 * p));
    float* pout = part + (size_t)z * (BATCH * N_H);
    const int orow = abase + wm * 64 + rhi * 4;
    const int ocol = cbase + wn * 64 + rlo;
#pragma unroll
    for (int i = 0; i < 4; ++i)
#pragma unroll
        for (int j = 0; j < 4; ++j)
#pragma unroll
            for (int r = 0; r < 4; ++r)
                pout[(size_t)(orow + i * 16 + r) * N_H + ocol + j * 16] =
                    (float)acc[i][j][r] * sc;
}

// ---------------------------------------------------------------------------
// layer-3 i8 GEMM (r4-proven)
// ---------------------------------------------------------------------------
__global__ __launch_bounds__(256, 2)
void gemm3_i8(const char* __restrict__ A, const char* __restrict__ W3p,
              float* __restrict__ part3, float s_base)
{
    __shared__ char As[128 * 64];
    __shared__ char Bs[64 * 64];

    const int tid  = threadIdx.x;
    const int wave = tid >> 6, lane = tid & 63;
    const int wm = wave >> 1, wn = wave & 1;

    const int rowbase = blockIdx.x * 128;
    const int z = blockIdx.y;
    const int p = z >> 1;
    const int kstart = (z & 1) * 2048;

    i32x4 acc[4][2];
#pragma unroll
    for (int i = 0; i < 4; ++i)
#pragma unroll
        for (int j = 0; j < 2; ++j) acc[i][j] = (i32x4)(0);

    const int soff0 = wave * 2048 + lane * 16;
    const int soff1 = soff0 + 1024;
    const int r0 = soff0 >> 6, kb0 = soff0 & 63;
    const int r1 = soff1 >> 6, kb1 = soff1 & 63;
    const int soffB = tid * 16;
    const int rB = soffB >> 6, kbB = soffB & 63;

    const size_t aoff0 = (size_t)(rowbase + r0) * 4096 + kb0;
    const size_t aoff1 = (size_t)(rowbase + r1) * 4096 + kb1;
    const size_t boff  = (size_t)rB * 4096 + kbB;

    const char* Bp = W3p + (size_t)p * 64 * 4096;

    char* ldsA0 = As + wave * 2048;
    char* ldsA1 = ldsA0 + 1024;
    char* ldsB  = Bs + wave * 1024;

    const int rlo = lane & 15, rhi = lane >> 4;
    const char* pAf = As + (wm * 64 + rlo) * 64 + rhi * 16;
    const char* pBf = Bs + (wn * 32 + rlo) * 64 + rhi * 16;

    for (int it = 0; it < 32; ++it) {
        const int k = kstart + it * 64;
        __syncthreads();
        GLL16(A + k + aoff0, ldsA0);
        GLL16(A + k + aoff1, ldsA1);
        GLL16(Bp + k + boff, ldsB);
        __syncthreads();

        i32x4 av[4], bv[2];
#pragma unroll
        for (int i = 0; i < 4; ++i) av[i] = *(const i32x4*)(pAf + i * 1024);
#pragma unroll
        for (int j = 0; j < 2; ++j) bv[j] = *(const i32x4*)(pBf + j * 1024);
#pragma unroll
        for (int i = 0; i < 4; ++i)
#pragma unroll
            for (int j = 0; j < 2; ++j)
                acc[i][j] = __builtin_amdgcn_mfma_i32_16x16x64_i8(
                    av[i], bv[j], acc[i][j], 0, 0, 0);
    }

    const float sc = s_base * (float)(65536 >> (8 * p));
    float* pout = part3 + (size_t)z * (12800 * 64);
    const int orow = rowbase + wm * 64 + rhi * 4;
    const int ocol = wn * 32 + rlo;
#pragma unroll
    for (int i = 0; i < 4; ++i)
#pragma unroll
        for (int j = 0; j < 2; ++j)
#pragma unroll
            for (int r = 0; r < 4; ++r)
                pout[(size_t)(orow + i * 16 + r) * 64 + ocol + j * 16] =
                    (float)acc[i][j][r] * sc;
}

// ---------------------------------------------------------------------------
// element-wise LIF bodies (float4 per thread over one 256x4096 slab)
// ---------------------------------------------------------------------------
__device__ inline void lif_elem4(float4 cur, float* __restrict__ mem,
                                 char* __restrict__ sout, size_t base)
{
    const float4 mp = *(const float4*)&mem[base];
    float4 mn;
    mn.x = 0.9f * mp.x + cur.x - ((mp.x > 1.0f) ? 1.0f : 0.0f);
    mn.y = 0.9f * mp.y + cur.y - ((mp.y > 1.0f) ? 1.0f : 0.0f);
    mn.z = 0.9f * mp.z + cur.z - ((mp.z > 1.0f) ? 1.0f : 0.0f);
    mn.w = 0.9f * mp.w + cur.w - ((mp.w > 1.0f) ? 1.0f : 0.0f);
    *(float4*)&mem[base] = mn;
    const uint32_t sp = (uint32_t)(mn.x > 1.0f) | ((uint32_t)(mn.y > 1.0f) << 8) |
                        ((uint32_t)(mn.z > 1.0f) << 16) | ((uint32_t)(mn.w > 1.0f) << 24);
    *(uint32_t*)&sout[base] = sp;
}

// lif1: cur = cur1slice + b1 -> m1, s1
__global__ __launch_bounds__(256)
void lif1_k(const float* __restrict__ cur1, const float* __restrict__ b1,
            float* __restrict__ m1, char* __restrict__ s1)
{
    const int i4 = blockIdx.x * 256 + threadIdx.x;
    const size_t base = (size_t)i4 * 4;
    const int col = (int)(base & (N_H - 1));
    const float4 bv = *(const float4*)&b1[col];
    const float4 cv = *(const float4*)&cur1[base];
    float4 cur = make_float4(cv.x + bv.x, cv.y + bv.y, cv.z + bv.z, cv.w + bv.w);
    lif_elem4(cur, m1, s1, base);
}

// reduce2: sum 6 partials + b2 -> m2, s2slab
__global__ __launch_bounds__(256)
void reduce2_k(const float* __restrict__ part, const float* __restrict__ b2,
               float* __restrict__ m2, char* __restrict__ s2)
{
    const int i4 = blockIdx.x * 256 + threadIdx.x;
    const size_t base = (size_t)i4 * 4;
    const int col = (int)(base & (N_H - 1));
    float4 cur = *(const float4*)&b2[col];
#pragma unroll
    for (int g = 0; g < 6; ++g) {
        const float4 pv = *(const float4*)&part[(size_t)g * (BATCH * N_H) + base];
        cur.x += pv.x; cur.y += pv.y; cur.z += pv.z; cur.w += pv.w;
    }
    lif_elem4(cur, m2, s2, base);
}

// fused: blocks [0,1024) = reduce2(t); blocks [1024,2048) = lif1(t+1)
__global__ __launch_bounds__(256)
void fused_r2_l1(const float* __restrict__ part, const float* __restrict__ b2,
                 float* __restrict__ m2, char* __restrict__ s2,
                 const float* __restrict__ cur1, const float* __restrict__ b1,
                 float* __restrict__ m1, char* __restrict__ s1)
{
    if (blockIdx.x < 1024) {
        const int i4 = blockIdx.x * 256 + threadIdx.x;
        const size_t base = (size_t)i4 * 4;
        const int col = (int)(base & (N_H - 1));
        float4 cur = *(const float4*)&b2[col];
#pragma unroll
        for (int g = 0; g < 6; ++g) {
            const float4 pv = *(const float4*)&part[(size_t)g * (BATCH * N_H) + base];
            cur.x += pv.x; cur.y += pv.y; cur.z += pv.z; cur.w += pv.w;
        }
        lif_elem4(cur, m2, s2, base);
    } else {
        const int i4 = (blockIdx.x - 1024) * 256 + threadIdx.x;
        const size_t base = (size_t)i4 * 4;
        const int col = (int)(base & (N_H - 1));
        const float4 bv = *(const float4*)&b1[col];
        const float4 cv = *(const float4*)&cur1[base];
        float4 cur = make_float4(cv.x + bv.x, cv.y + bv.y, cv.z + bv.z, cv.w + bv.w);
        lif_elem4(cur, m1, s1, base);
    }
}

// combine 6 group partials + bias, sequential LIF over t
template<int NG>
__global__ __launch_bounds__(256)
void lif3_scan(const float* __restrict__ part, const float* __restrict__ b3,
               float* __restrict__ out)
{
    const int g = blockIdx.x * 256 + threadIdx.x;
    const int j = g & 63;
    const int b = g >> 6;
    const float bj = b3[j];
    float m = 0.f, accum = 0.f;
    for (int t = 0; t < T_STEPS; ++t) {
        const size_t row = (size_t)t * 256 + b;
        float cur = bj;
#pragma unroll
        for (int q = 0; q < NG; ++q)
            cur += part[(size_t)q * (12800 * 64) + row * 64 + j];
        const float reset = (m > 1.0f) ? 1.0f : 0.0f;
        m = 0.9f * m + cur - reset;
        accum += (m > 1.0f) ? 1.0f : 0.0f;
    }
    out[g] = accum;
}

// ---------------------------------------------------------------------------
// fp32 fallback path (round 1) — used only if ws_size too small
// ---------------------------------------------------------------------------
template<int K, bool PACK_BITS>
__global__ __launch_bounds__(512)
void gemm_lif(const float* __restrict__ A, const float* __restrict__ W,
              const float* __restrict__ bias, float* __restrict__ mem,
              float* __restrict__ s_f32, uint32_t* __restrict__ s_bits)
{
    __shared__ float Asf[32][68];
    __shared__ float Wsf[32][68];
    __shared__ uint8_t us[64][64];

    const int tid = threadIdx.x;
    const int abase = blockIdx.y * 64;
    const int cbase = blockIdx.x * 64;
    const int tx = tid & 15;
    const int ty = tid >> 4;

    float acc[2][4];
#pragma unroll
    for (int i = 0; i < 2; ++i)
#pragma unroll
        for (int j = 0; j < 4; ++j) acc[i][j] = 0.f;

    const int lrow = tid >> 3;
    const int lg = tid & 7;

    for (int k0 = 0; k0 < K; k0 += 32) {
        const float4 av = *(const float4*)&A[(size_t)(abase + lrow) * K + k0 + lg * 4];
        const float4 wv = *(const float4*)&W[(size_t)(cbase + lrow) * K + k0 + lg * 4];
        __syncthreads();
        Asf[lg * 4 + 0][lrow] = av.x; Asf[lg * 4 + 1][lrow] = av.y;
        Asf[lg * 4 + 2][lrow] = av.z; Asf[lg * 4 + 3][lrow] = av.w;
        Wsf[lg * 4 + 0][lrow] = wv.x; Wsf[lg * 4 + 1][lrow] = wv.y;
        Wsf[lg * 4 + 2][lrow] = wv.z; Wsf[lg * 4 + 3][lrow] = wv.w;
        __syncthreads();
#pragma unroll
        for (int kk = 0; kk < 32; ++kk) {
            const float2 a2 = *(const float2*)&Asf[kk][ty * 2];
            const float4 b4 = *(const float4*)&Wsf[kk][tx * 4];
            acc[0][0] += a2.x * b4.x; acc[0][1] += a2.x * b4.y;
            acc[0][2] += a2.x * b4.z; acc[0][3] += a2.x * b4.w;
            acc[1][0] += a2.y * b4.x; acc[1][1] += a2.y * b4.y;
            acc[1][2] += a2.y * b4.z; acc[1][3] += a2.y * b4.w;
        }
    }

    const int r0 = abase + ty * 2;
    const int c0loc = tx * 4;
    const int c0 = cbase + c0loc;
    const float4 bv = *(const float4*)&bias[c0];

#pragma unroll
    for (int i = 0; i < 2; ++i) {
        const size_t off = (size_t)(r0 + i) * N_H + c0;
        const float4 mp = *(const float4*)&mem[off];
        float4 mn, sp;
        { float cur = acc[i][0] + bv.x;
          mn.x = 0.9f * mp.x + cur - ((mp.x > 1.0f) ? 1.0f : 0.0f);
          sp.x = (mn.x > 1.0f) ? 1.0f : 0.0f; }
        { float cur = acc[i][1] + bv.y;
          mn.y = 0.9f * mp.y + cur - ((mp.y > 1.0f) ? 1.0f : 0.0f);
          sp.y = (mn.y > 1.0f) ? 1.0f : 0.0f; }
        { float cur = acc[i][2] + bv.z;
          mn.z = 0.9f * mp.z + cur - ((mp.z > 1.0f) ? 1.0f : 0.0f);
          sp.z = (mn.z > 1.0f) ? 1.0f : 0.0f; }
        { float cur = acc[i][3] + bv.w;
          mn.w = 0.9f * mp.w + cur - ((mp.w > 1.0f) ? 1.0f : 0.0f);
          sp.w = (mn.w > 1.0f) ? 1.0f : 0.0f; }
        *(float4*)&mem[off] = mn;
        if constexpr (!PACK_BITS) {
            *(float4*)&s_f32[off] = sp;
        } else {
            us[ty * 2 + i][c0loc + 0] = (uint8_t)sp.x;
            us[ty * 2 + i][c0loc + 1] = (uint8_t)sp.y;
            us[ty * 2 + i][c0loc + 2] = (uint8_t)sp.z;
            us[ty * 2 + i][c0loc + 3] = (uint8_t)sp.w;
        }
    }

    if constexpr (PACK_BITS) {
        __syncthreads();
        if (tid < 128) {
            const int r = tid >> 1;
            const int w = tid & 1;
            uint32_t bits = 0;
#pragma unroll
            for (int b = 0; b < 32; ++b)
                bits |= ((uint32_t)us[r][w * 32 + b]) << b;
            s_bits[(size_t)(abase + r) * 128 + (cbase >> 5) + w] = bits;
        }
    }
}

__global__ __launch_bounds__(256)
void gemm3_bits(const uint32_t* __restrict__ s_bits, const float* __restrict__ W3,
                float* __restrict__ part)
{
    __shared__ float Asf[32][68];
    __shared__ float Wsf[32][68];

    const int tid = threadIdx.x;
    const int rowbase = blockIdx.x * 64;
    const int ks = blockIdx.y;
    const int tx = tid & 15;
    const int ty = tid >> 4;

    float acc[4][4];
#pragma unroll
    for (int i = 0; i < 4; ++i)
#pragma unroll
        for (int j = 0; j < 4; ++j) acc[i][j] = 0.f;

    const int r  = tid & 63;
    const int q  = tid >> 6;
    const int wr = tid >> 3;
    const int wg = tid & 7;

    for (int c = 0; c < 32; ++c) {
        const int k0 = ks * 1024 + c * 32;
        const uint32_t word = s_bits[(size_t)(rowbase + r) * 128 + (k0 >> 5)];
        const float4 wv0 = *(const float4*)&W3[(size_t)wr * 4096 + k0 + wg * 4];
        const float4 wv1 = *(const float4*)&W3[(size_t)(wr + 32) * 4096 + k0 + wg * 4];
        __syncthreads();
#pragma unroll
        for (int u = 0; u < 8; ++u)
            Asf[q * 8 + u][r] = (float)((word >> (q * 8 + u)) & 1u);
        Wsf[wg * 4 + 0][wr] = wv0.x;
        Wsf[wg * 4 + 1][wr] = wv0.y;
        Wsf[wg * 4 + 2][wr] = wv0.z;
        Wsf[wg * 4 + 3][wr] = wv0.w;
        Wsf[wg * 4 + 0][wr + 32] = wv1.x;
        Wsf[wg * 4 + 1][wr + 32] = wv1.y;
        Wsf[wg * 4 + 2][wr + 32] = wv1.z;
        Wsf[wg * 4 + 3][wr + 32] = wv1.w;
        __syncthreads();
#pragma unroll
        for (int kk = 0; kk < 32; ++kk) {
            const float4 a4 = *(const float4*)&Asf[kk][ty * 4];
            const float4 b4 = *(const float4*)&Wsf[kk][tx * 4];
            acc[0][0] += a4.x * b4.x; acc[0][1] += a4.x * b4.y;
            acc[0][2] += a4.x * b4.z; acc[0][3] += a4.x * b4.w;
            acc[1][0] += a4.y * b4.x; acc[1][1] += a4.y * b4.y;
            acc[1][2] += a4.y * b4.z; acc[1][3] += a4.y * b4.w;
            acc[2][0] += a4.z * b4.x; acc[2][1] += a4.z * b4.y;
            acc[2][2] += a4.z * b4.z; acc[2][3] += a4.z * b4.w;
            acc[3][0] += a4.w * b4.x; acc[3][1] += a4.w * b4.y;
            acc[3][2] += a4.w * b4.z; acc[3][3] += a4.w * b4.w;
        }
    }
#pragma unroll
    for (int i = 0; i < 4; ++i) {
        float4 v = make_float4(acc[i][0], acc[i][1], acc[i][2], acc[i][3]);
        *(float4*)&part[((size_t)ks * 12800 + rowbase + ty * 4 + i) * 64 + tx * 4] = v;
    }
}

// ---------------------------------------------------------------------------
extern "C" void kernel_launch(void* const* d_in, const int* in_sizes, int n_in,
                              void* d_out, int out_size, void* d_ws, size_t ws_size,
                              hipStream_t stream)
{
    const float* x  = (const float*)d_in[0];
    const float* W1 = (const float*)d_in[1];
    const float* b1 = (const float*)d_in[2];
    const float* W2 = (const float*)d_in[3];
    const float* b2 = (const float*)d_in[4];
    const float* W3 = (const float*)d_in[5];
    const float* b3 = (const float*)d_in[6];

    char* ws = (char*)d_ws;

    const size_t oW1p  = 0;              //  18,874,368
    const size_t oW2p  = 18874368;       //  50,331,648
    const size_t oW3p  = 69206016;       //     786,432
    const size_t oXi8  = 69992448;       //  19,660,800
    const size_t oS1   = 89653248;       //   1,048,576
    const size_t oS2   = 90701824;       //  52,428,800
    const size_t oM1   = 143130624;      //   4,194,304
    const size_t oM2   = 147324928;      //   4,194,304
    const size_t oPart = 151519232;      //  33,554,432 (z=6 uses 24 MB; part3 aliases)
    const size_t oCur1 = 185073664;      // 104,857,600 (25 steps x 256 x 4096 f32)
    const size_t NEED  = 289931264;

    const double bnd1 = 1.0 / sqrt(1536.0);
    const double bnd2 = 1.0 / 64.0;
    const double bnd3 = 1.0 / 64.0;
    const float inv1 = (float)((double)DEN / bnd1), sb1 = (float)(bnd1 / (double)DEN);
    const float inv2 = (float)((double)DEN / bnd2), sb2 = (float)(bnd2 / (double)DEN);
    const float inv3 = (float)((double)DEN / bnd3), sb3 = (float)(bnd3 / (double)DEN);

    if (ws_size >= NEED) {
        char*  W1p  = ws + oW1p;
        char*  W2p  = ws + oW2p;
        char*  W3p  = ws + oW3p;
        char*  xi8  = ws + oXi8;
        char*  s1   = ws + oS1;
        char*  s2   = ws + oS2;
        float* m1   = (float*)(ws + oM1);
        float* m2   = (float*)(ws + oM2);
        float* part = (float*)(ws + oPart);
        float* cur1 = (float*)(ws + oCur1);
        float* part3 = part;

        split3_i8<<<6144, 256, 0, stream>>>((const float4*)W1, W1p,
                                            (size_t)4096 * 1536, inv1);
        split3_i8<<<16384, 256, 0, stream>>>((const float4*)W2, W2p,
                                             (size_t)4096 * 4096, inv2);
        split3_i8<<<256, 256, 0, stream>>>((const float4*)W3, W3p,
                                           (size_t)64 * 4096, inv3);
        xcvt_i8<<<19200, 256, 0, stream>>>((const float4*)x, (uint32_t*)xi8);
        zero_ws<<<2048, 256, 0, stream>>>((float4*)m1);   // m1 + m2 contiguous

        const size_t slab = (size_t)BATCH * N_H;   // elems per step
        for (int chunk = 0; chunk < 2; ++chunk) {
            // batched layer-1 over 25 steps: rows 6400, no split-K
            gemm1_full<<<dim3(32, 50), 256, 0, stream>>>(
                xi8 + (size_t)chunk * 25 * BATCH * 1536, W1p, cur1, sb1);
            lif1_k<<<1024, 256, 0, stream>>>(cur1, b1, m1, s1);
            for (int i = 0; i < 25; ++i) {
                const int t = chunk * 25 + i;
                gemm_i8<4096><<<dim3(32, 2, 6), 256, 0, stream>>>(
                    s1, W2p, part, sb2);
                if (i < 24) {
                    fused_r2_l1<<<2048, 256, 0, stream>>>(
                        part, b2, m2, s2 + (size_t)t * slab,
                        cur1 + (size_t)(i + 1) * slab, b1, m1, s1);
                } else {
                    reduce2_k<<<1024, 256, 0, stream>>>(
                        part, b2, m2, s2 + (size_t)t * slab);
                }
            }
        }
        gemm3_i8<<<dim3(100, 6), 256, 0, stream>>>(s2, W3p, part3, sb3);
        lif3_scan<6><<<64, 256, 0, stream>>>(part3, b3, (float*)d_out);
    } else {
        float*    m1     = (float*)(ws);
        float*    m2     = (float*)(ws + (size_t)4 * 1024 * 1024);
        float*    s1f    = (float*)(ws + (size_t)8 * 1024 * 1024);
        uint32_t* s2bits = (uint32_t*)(ws + (size_t)12 * 1024 * 1024);
        float*    part   = (float*)(ws + (size_t)20 * 1024 * 1024);

        zero_ws<<<2048, 256, 0, stream>>>((float4*)m1);
        for (int t = 0; t < T_STEPS; ++t) {
            gemm_lif<1536, false><<<dim3(64, 4), 512, 0, stream>>>(
                x + (size_t)t * BATCH * 1536, W1, b1, m1, s1f, nullptr);
            gemm_lif<4096, true><<<dim3(64, 4), 512, 0, stream>>>(
                s1f, W2, b2, m2, nullptr, s2bits + (size_t)t * BATCH * 128);
        }
        gemm3_bits<<<dim3(200, 4), 256, 0, stream>>>(s2bits, W3, part);
        lif3_scan<4><<<64, 256, 0, stream>>>(part, b3, (float*)d_out);
    }
}

// Round 7
// 2192.184 us; speedup vs baseline: 1.3936x; 1.0393x over previous
//
#include <hip/hip_runtime.h>
#include <stdint.h>
#include <stddef.h>
#include <math.h>

// ContextSNN round 7: r6 structure + (a) XOR bank-conflict swizzle on all MFMA
// LDS tiles, (b) XCD-aware block swizzle for W locality in per-XCD L2.
// T=50, B=256, IN=1536, H1=H2=4096, OUT=64. LIF beta=0.9, thr=1, subtract.

#define T_STEPS 50
#define BATCH   256
#define N_H     4096
#define DEN     8355711   // 127*65536 + 127*256 + 127

typedef unsigned short u16;
typedef __attribute__((ext_vector_type(4))) int i32x4;
typedef __attribute__((ext_vector_type(4))) float f32x4;

#define GLL16(gp, lp) __builtin_amdgcn_global_load_lds( \
    (const __attribute__((address_space(1))) void*)(gp), \
    (__attribute__((address_space(3))) void*)(lp), 16, 0, 0)

// ---------------------------------------------------------------------------
// prep
// ---------------------------------------------------------------------------
__global__ __launch_bounds__(256) void zero_ws(float4* __restrict__ p) {
    p[(size_t)blockIdx.x * 256 + threadIdx.x] = make_float4(0.f, 0.f, 0.f, 0.f);
}

__device__ inline void digits3(float w, float inv_s, int& h, int& m, int& l) {
    int V = (int)rintf(w * inv_s);
    V = min(max(V, -DEN), DEN);
    l = ((V + 128) & 255) - 128;
    const int V2 = (V - l) >> 8;
    m = ((V2 + 128) & 255) - 128;
    h = (V2 - m) >> 8;
}

__global__ __launch_bounds__(256)
void split3_i8(const float4* __restrict__ W, char* __restrict__ P,
               size_t plane_elems, float inv_s)
{
    const size_t i = (size_t)blockIdx.x * 256 + threadIdx.x;
    const float4 w = W[i];
    int h0,m0,l0,h1,m1,l1,h2,m2,l2,h3,m3,l3;
    digits3(w.x, inv_s, h0, m0, l0);
    digits3(w.y, inv_s, h1, m1, l1);
    digits3(w.z, inv_s, h2, m2, l2);
    digits3(w.w, inv_s, h3, m3, l3);
    const uint32_t ph = (uint32_t)(uint8_t)h0 | ((uint32_t)(uint8_t)h1 << 8) |
                        ((uint32_t)(uint8_t)h2 << 16) | ((uint32_t)(uint8_t)h3 << 24);
    const uint32_t pm = (uint32_t)(uint8_t)m0 | ((uint32_t)(uint8_t)m1 << 8) |
                        ((uint32_t)(uint8_t)m2 << 16) | ((uint32_t)(uint8_t)m3 << 24);
    const uint32_t pl = (uint32_t)(uint8_t)l0 | ((uint32_t)(uint8_t)l1 << 8) |
                        ((uint32_t)(uint8_t)l2 << 16) | ((uint32_t)(uint8_t)l3 << 24);
    *(uint32_t*)&P[4 * i]                   = ph;
    *(uint32_t*)&P[plane_elems + 4 * i]     = pm;
    *(uint32_t*)&P[2 * plane_elems + 4 * i] = pl;
}

__global__ __launch_bounds__(256)
void xcvt_i8(const float4* __restrict__ in, uint32_t* __restrict__ out) {
    const size_t i = (size_t)blockIdx.x * 256 + threadIdx.x;
    const float4 v = in[i];
    out[i] = (uint32_t)(v.x > 0.5f) | ((uint32_t)(v.y > 0.5f) << 8) |
             ((uint32_t)(v.z > 0.5f) << 16) | ((uint32_t)(v.w > 0.5f) << 24);
}

// ---------------------------------------------------------------------------
// Layer-1 batched GEMM: A[6400][1536] x W1p[3][4096][1536]^T, plane-fold.
// 1-D grid 1600, XCD swizzle: col=(bid&7)*4+((bid>>3)&3), row=bid>>5.
// XOR swizzle: chunk stored at c ^ ((row>>1)&3).
// ---------------------------------------------------------------------------
__global__ __launch_bounds__(256, 2)
void gemm1_full(const char* __restrict__ A, const char* __restrict__ Wp,
                float* __restrict__ cur, float s_base)
{
    const int K = 1536, F = 4608;
    __shared__ char As[128 * 64];
    __shared__ char Bs[128 * 64];

    const int tid  = threadIdx.x;
    const int wave = tid >> 6, lane = tid & 63;
    const int wm = wave >> 1, wn = wave & 1;

    const int bid   = blockIdx.x;
    const int cbase = (((bid & 7) << 2) + ((bid >> 3) & 3)) * 128;  // 32 col tiles
    const int abase = (bid >> 5) * 128;                             // 50 row tiles

    int p = 0, k = 0;

    i32x4 acc[4][4];
    f32x4 facc[4][4];
#pragma unroll
    for (int i = 0; i < 4; ++i)
#pragma unroll
        for (int j = 0; j < 4; ++j) { acc[i][j] = (i32x4)(0); facc[i][j] = (f32x4)(0.f); }

    const int soff0 = wave * 2048 + lane * 16;
    const int soff1 = soff0 + 1024;
    const int r0 = soff0 >> 6, r1 = soff1 >> 6;
    const int kb0 = ((((soff0 >> 4) & 3) ^ ((r0 >> 1) & 3)) << 4);  // swizzled src chunk
    const int kb1 = ((((soff1 >> 4) & 3) ^ ((r1 >> 1) & 3)) << 4);

    const size_t aoff0 = (size_t)(abase + r0) * K + kb0;
    const size_t aoff1 = (size_t)(abase + r1) * K + kb1;
    const size_t boff0 = (size_t)(cbase + r0) * K + kb0;
    const size_t boff1 = (size_t)(cbase + r1) * K + kb1;

    char* ldsA0 = As + wave * 2048;
    char* ldsA1 = ldsA0 + 1024;
    char* ldsB0 = Bs + wave * 2048;
    char* ldsB1 = ldsB0 + 1024;

    const int rlo = lane & 15, rhi = lane >> 4;
    const int qr = (rlo >> 1) & 3;
    const char* pAf = As + (wm * 64 + rlo) * 64 + ((rhi ^ qr) << 4);
    const char* pBf = Bs + (wn * 64 + rlo) * 64 + ((rhi ^ qr) << 4);

    for (int f = 0; f < F; f += 64) {
        const char* ak = A + k;
        const char* bk = Wp + (size_t)p * N_H * K + k;
        __syncthreads();
        GLL16(ak + aoff0, ldsA0);
        GLL16(ak + aoff1, ldsA1);
        GLL16(bk + boff0, ldsB0);
        GLL16(bk + boff1, ldsB1);
        __syncthreads();

        i32x4 av[4], bv[4];
#pragma unroll
        for (int i = 0; i < 4; ++i) av[i] = *(const i32x4*)(pAf + i * 1024);
#pragma unroll
        for (int j = 0; j < 4; ++j) bv[j] = *(const i32x4*)(pBf + j * 1024);
#pragma unroll
        for (int i = 0; i < 4; ++i)
#pragma unroll
            for (int j = 0; j < 4; ++j)
                acc[i][j] = __builtin_amdgcn_mfma_i32_16x16x64_i8(
                    av[i], bv[j], acc[i][j], 0, 0, 0);

        k += 64;
        if (k >= K) {   // plane boundary: fold exact i32 segment into f32
            const float sc = s_base * (float)(65536 >> (8 * p));
#pragma unroll
            for (int i = 0; i < 4; ++i)
#pragma unroll
                for (int j = 0; j < 4; ++j) {
#pragma unroll
                    for (int r = 0; r < 4; ++r)
                        facc[i][j][r] += sc * (float)acc[i][j][r];
                    acc[i][j] = (i32x4)(0);
                }
            k = 0; ++p;
        }
    }

    const int orow = abase + wm * 64 + rhi * 4;
    const int ocol = cbase + wn * 64 + rlo;
#pragma unroll
    for (int i = 0; i < 4; ++i)
#pragma unroll
        for (int j = 0; j < 4; ++j)
#pragma unroll
            for (int r = 0; r < 4; ++r)
                cur[(size_t)(orow + i * 16 + r) * N_H + ocol + j * 16] = facc[i][j][r];
}

// ---------------------------------------------------------------------------
// Layer-2 GEMM: z = plane*2 + K-half, plane-aligned. 1-D grid 384 with XCD
// swizzle: col=(bid&7)*4+((bid>>3)&3), m=(bid>>5)&1, z=bid>>6.
// ---------------------------------------------------------------------------
template<int K>
__global__ __launch_bounds__(256, 2)
void gemm_i8(const char* __restrict__ A, const char* __restrict__ Wp,
             float* __restrict__ part, float s_base)
{
    __shared__ char As[128 * 64];
    __shared__ char Bs[128 * 64];

    const int tid  = threadIdx.x;
    const int wave = tid >> 6, lane = tid & 63;
    const int wm = wave >> 1, wn = wave & 1;

    const int bid   = blockIdx.x;
    const int cbase = (((bid & 7) << 2) + ((bid >> 3) & 3)) * 128;
    const int abase = ((bid >> 5) & 1) * 128;
    const int z     = bid >> 6;        // 0..5
    const int p = z >> 1;
    const int kstart = (z & 1) * (K / 2);

    i32x4 acc[4][4];
#pragma unroll
    for (int i = 0; i < 4; ++i)
#pragma unroll
        for (int j = 0; j < 4; ++j) acc[i][j] = (i32x4)(0);

    const int soff0 = wave * 2048 + lane * 16;
    const int soff1 = soff0 + 1024;
    const int r0 = soff0 >> 6, r1 = soff1 >> 6;
    const int kb0 = ((((soff0 >> 4) & 3) ^ ((r0 >> 1) & 3)) << 4);
    const int kb1 = ((((soff1 >> 4) & 3) ^ ((r1 >> 1) & 3)) << 4);

    const size_t aoff0 = (size_t)(abase + r0) * K + kb0;
    const size_t aoff1 = (size_t)(abase + r1) * K + kb1;
    const size_t boff0 = (size_t)(cbase + r0) * K + kb0;
    const size_t boff1 = (size_t)(cbase + r1) * K + kb1;

    const char* Bp = Wp + (size_t)p * N_H * K;

    char* ldsA0 = As + wave * 2048;
    char* ldsA1 = ldsA0 + 1024;
    char* ldsB0 = Bs + wave * 2048;
    char* ldsB1 = ldsB0 + 1024;

    const int rlo = lane & 15, rhi = lane >> 4;
    const int qr = (rlo >> 1) & 3;
    const char* pAf = As + (wm * 64 + rlo) * 64 + ((rhi ^ qr) << 4);
    const char* pBf = Bs + (wn * 64 + rlo) * 64 + ((rhi ^ qr) << 4);

#pragma unroll 2
    for (int it = 0; it < K / 128; ++it) {
        const int k = kstart + it * 64;
        const char* ak = A + k;
        const char* bk = Bp + k;
        __syncthreads();
        GLL16(ak + aoff0, ldsA0);
        GLL16(ak + aoff1, ldsA1);
        GLL16(bk + boff0, ldsB0);
        GLL16(bk + boff1, ldsB1);
        __syncthreads();

        i32x4 av[4], bv[4];
#pragma unroll
        for (int i = 0; i < 4; ++i) av[i] = *(const i32x4*)(pAf + i * 1024);
#pragma unroll
        for (int j = 0; j < 4; ++j) bv[j] = *(const i32x4*)(pBf + j * 1024);
#pragma unroll
        for (int i = 0; i < 4; ++i)
#pragma unroll
            for (int j = 0; j < 4; ++j)
                acc[i][j] = __builtin_amdgcn_mfma_i32_16x16x64_i8(
                    av[i], bv[j], acc[i][j], 0, 0, 0);
    }

    const float sc = s_base * (float)(65536 >> (8 * p));
    float* pout = part + (size_t)z * (BATCH * N_H);
    const int orow = abase + wm * 64 + rhi * 4;
    const int ocol = cbase + wn * 64 + rlo;
#pragma unroll
    for (int i = 0; i < 4; ++i)
#pragma unroll
        for (int j = 0; j < 4; ++j)
#pragma unroll
            for (int r = 0; r < 4; ++r)
                pout[(size_t)(orow + i * 16 + r) * N_H + ocol + j * 16] =
                    (float)acc[i][j][r] * sc;
}

// ---------------------------------------------------------------------------
// layer-3 i8 GEMM (+ XOR swizzle)
// ---------------------------------------------------------------------------
__global__ __launch_bounds__(256, 2)
void gemm3_i8(const char* __restrict__ A, const char* __restrict__ W3p,
              float* __restrict__ part3, float s_base)
{
    __shared__ char As[128 * 64];
    __shared__ char Bs[64 * 64];

    const int tid  = threadIdx.x;
    const int wave = tid >> 6, lane = tid & 63;
    const int wm = wave >> 1, wn = wave & 1;

    const int rowbase = blockIdx.x * 128;
    const int z = blockIdx.y;
    const int p = z >> 1;
    const int kstart = (z & 1) * 2048;

    i32x4 acc[4][2];
#pragma unroll
    for (int i = 0; i < 4; ++i)
#pragma unroll
        for (int j = 0; j < 2; ++j) acc[i][j] = (i32x4)(0);

    const int soff0 = wave * 2048 + lane * 16;
    const int soff1 = soff0 + 1024;
    const int r0 = soff0 >> 6, r1 = soff1 >> 6;
    const int kb0 = ((((soff0 >> 4) & 3) ^ ((r0 >> 1) & 3)) << 4);
    const int kb1 = ((((soff1 >> 4) & 3) ^ ((r1 >> 1) & 3)) << 4);
    const int soffB = tid * 16;
    const int rB = soffB >> 6;
    const int kbB = ((((soffB >> 4) & 3) ^ ((rB >> 1) & 3)) << 4);

    const size_t aoff0 = (size_t)(rowbase + r0) * 4096 + kb0;
    const size_t aoff1 = (size_t)(rowbase + r1) * 4096 + kb1;
    const size_t boff  = (size_t)rB * 4096 + kbB;

    const char* Bp = W3p + (size_t)p * 64 * 4096;

    char* ldsA0 = As + wave * 2048;
    char* ldsA1 = ldsA0 + 1024;
    char* ldsB  = Bs + wave * 1024;

    const int rlo = lane & 15, rhi = lane >> 4;
    const int qr = (rlo >> 1) & 3;
    const char* pAf = As + (wm * 64 + rlo) * 64 + ((rhi ^ qr) << 4);
    const char* pBf = Bs + (wn * 32 + rlo) * 64 + ((rhi ^ qr) << 4);

    for (int it = 0; it < 32; ++it) {
        const int k = kstart + it * 64;
        __syncthreads();
        GLL16(A + k + aoff0, ldsA0);
        GLL16(A + k + aoff1, ldsA1);
        GLL16(Bp + k + boff, ldsB);
        __syncthreads();

        i32x4 av[4], bv[2];
#pragma unroll
        for (int i = 0; i < 4; ++i) av[i] = *(const i32x4*)(pAf + i * 1024);
#pragma unroll
        for (int j = 0; j < 2; ++j) bv[j] = *(const i32x4*)(pBf + j * 1024);
#pragma unroll
        for (int i = 0; i < 4; ++i)
#pragma unroll
            for (int j = 0; j < 2; ++j)
                acc[i][j] = __builtin_amdgcn_mfma_i32_16x16x64_i8(
                    av[i], bv[j], acc[i][j], 0, 0, 0);
    }

    const float sc = s_base * (float)(65536 >> (8 * p));
    float* pout = part3 + (size_t)z * (12800 * 64);
    const int orow = rowbase + wm * 64 + rhi * 4;
    const int ocol = wn * 32 + rlo;
#pragma unroll
    for (int i = 0; i < 4; ++i)
#pragma unroll
        for (int j = 0; j < 2; ++j)
#pragma unroll
            for (int r = 0; r < 4; ++r)
                pout[(size_t)(orow + i * 16 + r) * 64 + ocol + j * 16] =
                    (float)acc[i][j][r] * sc;
}

// ---------------------------------------------------------------------------
// element-wise LIF bodies
// ---------------------------------------------------------------------------
__device__ inline void lif_elem4(float4 cur, float* __restrict__ mem,
                                 char* __restrict__ sout, size_t base)
{
    const float4 mp = *(const float4*)&mem[base];
    float4 mn;
    mn.x = 0.9f * mp.x + cur.x - ((mp.x > 1.0f) ? 1.0f : 0.0f);
    mn.y = 0.9f * mp.y + cur.y - ((mp.y > 1.0f) ? 1.0f : 0.0f);
    mn.z = 0.9f * mp.z + cur.z - ((mp.z > 1.0f) ? 1.0f : 0.0f);
    mn.w = 0.9f * mp.w + cur.w - ((mp.w > 1.0f) ? 1.0f : 0.0f);
    *(float4*)&mem[base] = mn;
    const uint32_t sp = (uint32_t)(mn.x > 1.0f) | ((uint32_t)(mn.y > 1.0f) << 8) |
                        ((uint32_t)(mn.z > 1.0f) << 16) | ((uint32_t)(mn.w > 1.0f) << 24);
    *(uint32_t*)&sout[base] = sp;
}

__global__ __launch_bounds__(256)
void lif1_k(const float* __restrict__ cur1, const float* __restrict__ b1,
            float* __restrict__ m1, char* __restrict__ s1)
{
    const int i4 = blockIdx.x * 256 + threadIdx.x;
    const size_t base = (size_t)i4 * 4;
    const int col = (int)(base & (N_H - 1));
    const float4 bv = *(const float4*)&b1[col];
    const float4 cv = *(const float4*)&cur1[base];
    float4 cur = make_float4(cv.x + bv.x, cv.y + bv.y, cv.z + bv.z, cv.w + bv.w);
    lif_elem4(cur, m1, s1, base);
}

__global__ __launch_bounds__(256)
void reduce2_k(const float* __restrict__ part, const float* __restrict__ b2,
               float* __restrict__ m2, char* __restrict__ s2)
{
    const int i4 = blockIdx.x * 256 + threadIdx.x;
    const size_t base = (size_t)i4 * 4;
    const int col = (int)(base & (N_H - 1));
    float4 cur = *(const float4*)&b2[col];
#pragma unroll
    for (int g = 0; g < 6; ++g) {
        const float4 pv = *(const float4*)&part[(size_t)g * (BATCH * N_H) + base];
        cur.x += pv.x; cur.y += pv.y; cur.z += pv.z; cur.w += pv.w;
    }
    lif_elem4(cur, m2, s2, base);
}

__global__ __launch_bounds__(256)
void fused_r2_l1(const float* __restrict__ part, const float* __restrict__ b2,
                 float* __restrict__ m2, char* __restrict__ s2,
                 const float* __restrict__ cur1, const float* __restrict__ b1,
                 float* __restrict__ m1, char* __restrict__ s1)
{
    if (blockIdx.x < 1024) {
        const int i4 = blockIdx.x * 256 + threadIdx.x;
        const size_t base = (size_t)i4 * 4;
        const int col = (int)(base & (N_H - 1));
        float4 cur = *(const float4*)&b2[col];
#pragma unroll
        for (int g = 0; g < 6; ++g) {
            const float4 pv = *(const float4*)&part[(size_t)g * (BATCH * N_H) + base];
            cur.x += pv.x; cur.y += pv.y; cur.z += pv.z; cur.w += pv.w;
        }
        lif_elem4(cur, m2, s2, base);
    } else {
        const int i4 = (blockIdx.x - 1024) * 256 + threadIdx.x;
        const size_t base = (size_t)i4 * 4;
        const int col = (int)(base & (N_H - 1));
        const float4 bv = *(const float4*)&b1[col];
        const float4 cv = *(const float4*)&cur1[base];
        float4 cur = make_float4(cv.x + bv.x, cv.y + bv.y, cv.z + bv.z, cv.w + bv.w);
        lif_elem4(cur, m1, s1, base);
    }
}

template<int NG>
__global__ __launch_bounds__(256)
void lif3_scan(const float* __restrict__ part, const float* __restrict__ b3,
               float* __restrict__ out)
{
    const int g = blockIdx.x * 256 + threadIdx.x;
    const int j = g & 63;
    const int b = g >> 6;
    const float bj = b3[j];
    float m = 0.f, accum = 0.f;
    for (int t = 0; t < T_STEPS; ++t) {
        const size_t row = (size_t)t * 256 + b;
        float cur = bj;
#pragma unroll
        for (int q = 0; q < NG; ++q)
            cur += part[(size_t)q * (12800 * 64) + row * 64 + j];
        const float reset = (m > 1.0f) ? 1.0f : 0.0f;
        m = 0.9f * m + cur - reset;
        accum += (m > 1.0f) ? 1.0f : 0.0f;
    }
    out[g] = accum;
}

// ---------------------------------------------------------------------------
// fp32 fallback path (round 1) — used only if ws_size too small
// ---------------------------------------------------------------------------
template<int K, bool PACK_BITS>
__global__ __launch_bounds__(512)
void gemm_lif(const float* __restrict__ A, const float* __restrict__ W,
              const float* __restrict__ bias, float* __restrict__ mem,
              float* __restrict__ s_f32, uint32_t* __restrict__ s_bits)
{
    __shared__ float Asf[32][68];
    __shared__ float Wsf[32][68];
    __shared__ uint8_t us[64][64];

    const int tid = threadIdx.x;
    const int abase = blockIdx.y * 64;
    const int cbase = blockIdx.x * 64;
    const int tx = tid & 15;
    const int ty = tid >> 4;

    float acc[2][4];
#pragma unroll
    for (int i = 0; i < 2; ++i)
#pragma unroll
        for (int j = 0; j < 4; ++j) acc[i][j] = 0.f;

    const int lrow = tid >> 3;
    const int lg = tid & 7;

    for (int k0 = 0; k0 < K; k0 += 32) {
        const float4 av = *(const float4*)&A[(size_t)(abase + lrow) * K + k0 + lg * 4];
        const float4 wv = *(const float4*)&W[(size_t)(cbase + lrow) * K + k0 + lg * 4];
        __syncthreads();
        Asf[lg * 4 + 0][lrow] = av.x; Asf[lg * 4 + 1][lrow] = av.y;
        Asf[lg * 4 + 2][lrow] = av.z; Asf[lg * 4 + 3][lrow] = av.w;
        Wsf[lg * 4 + 0][lrow] = wv.x; Wsf[lg * 4 + 1][lrow] = wv.y;
        Wsf[lg * 4 + 2][lrow] = wv.z; Wsf[lg * 4 + 3][lrow] = wv.w;
        __syncthreads();
#pragma unroll
        for (int kk = 0; kk < 32; ++kk) {
            const float2 a2 = *(const float2*)&Asf[kk][ty * 2];
            const float4 b4 = *(const float4*)&Wsf[kk][tx * 4];
            acc[0][0] += a2.x * b4.x; acc[0][1] += a2.x * b4.y;
            acc[0][2] += a2.x * b4.z; acc[0][3] += a2.x * b4.w;
            acc[1][0] += a2.y * b4.x; acc[1][1] += a2.y * b4.y;
            acc[1][2] += a2.y * b4.z; acc[1][3] += a2.y * b4.w;
        }
    }

    const int r0 = abase + ty * 2;
    const int c0loc = tx * 4;
    const int c0 = cbase + c0loc;
    const float4 bv = *(const float4*)&bias[c0];

#pragma unroll
    for (int i = 0; i < 2; ++i) {
        const size_t off = (size_t)(r0 + i) * N_H + c0;
        const float4 mp = *(const float4*)&mem[off];
        float4 mn, sp;
        { float cur = acc[i][0] + bv.x;
          mn.x = 0.9f * mp.x + cur - ((mp.x > 1.0f) ? 1.0f : 0.0f);
          sp.x = (mn.x > 1.0f) ? 1.0f : 0.0f; }
        { float cur = acc[i][1] + bv.y;
          mn.y = 0.9f * mp.y + cur - ((mp.y > 1.0f) ? 1.0f : 0.0f);
          sp.y = (mn.y > 1.0f) ? 1.0f : 0.0f; }
        { float cur = acc[i][2] + bv.z;
          mn.z = 0.9f * mp.z + cur - ((mp.z > 1.0f) ? 1.0f : 0.0f);
          sp.z = (mn.z > 1.0f) ? 1.0f : 0.0f; }
        { float cur = acc[i][3] + bv.w;
          mn.w = 0.9f * mp.w + cur - ((mp.w > 1.0f) ? 1.0f : 0.0f);
          sp.w = (mn.w > 1.0f) ? 1.0f : 0.0f; }
        *(float4*)&mem[off] = mn;
        if constexpr (!PACK_BITS) {
            *(float4*)&s_f32[off] = sp;
        } else {
            us[ty * 2 + i][c0loc + 0] = (uint8_t)sp.x;
            us[ty * 2 + i][c0loc + 1] = (uint8_t)sp.y;
            us[ty * 2 + i][c0loc + 2] = (uint8_t)sp.z;
            us[ty * 2 + i][c0loc + 3] = (uint8_t)sp.w;
        }
    }

    if constexpr (PACK_BITS) {
        __syncthreads();
        if (tid < 128) {
            const int r = tid >> 1;
            const int w = tid & 1;
            uint32_t bits = 0;
#pragma unroll
            for (int b = 0; b < 32; ++b)
                bits |= ((uint32_t)us[r][w * 32 + b]) << b;
            s_bits[(size_t)(abase + r) * 128 + (cbase >> 5) + w] = bits;
        }
    }
}

__global__ __launch_bounds__(256)
void gemm3_bits(const uint32_t* __restrict__ s_bits, const float* __restrict__ W3,
                float* __restrict__ part)
{
    __shared__ float Asf[32][68];
    __shared__ float Wsf[32][68];

    const int tid = threadIdx.x;
    const int rowbase = blockIdx.x * 64;
    const int ks = blockIdx.y;
    const int tx = tid & 15;
    const int ty = tid >> 4;

    float acc[4][4];
#pragma unroll
    for (int i = 0; i < 4; ++i)
#pragma unroll
        for (int j = 0; j < 4; ++j) acc[i][j] = 0.f;

    const int r  = tid & 63;
    const int q  = tid >> 6;
    const int wr = tid >> 3;
    const int wg = tid & 7;

    for (int c = 0; c < 32; ++c) {
        const int k0 = ks * 1024 + c * 32;
        const uint32_t word = s_bits[(size_t)(rowbase + r) * 128 + (k0 >> 5)];
        const float4 wv0 = *(const float4*)&W3[(size_t)wr * 4096 + k0 + wg * 4];
        const float4 wv1 = *(const float4*)&W3[(size_t)(wr + 32) * 4096 + k0 + wg * 4];
        __syncthreads();
#pragma unroll
        for (int u = 0; u < 8; ++u)
            Asf[q * 8 + u][r] = (float)((word >> (q * 8 + u)) & 1u);
        Wsf[wg * 4 + 0][wr] = wv0.x;
        Wsf[wg * 4 + 1][wr] = wv0.y;
        Wsf[wg * 4 + 2][wr] = wv0.z;
        Wsf[wg * 4 + 3][wr] = wv0.w;
        Wsf[wg * 4 + 0][wr + 32] = wv1.x;
        Wsf[wg * 4 + 1][wr + 32] = wv1.y;
        Wsf[wg * 4 + 2][wr + 32] = wv1.z;
        Wsf[wg * 4 + 3][wr + 32] = wv1.w;
        __syncthreads();
#pragma unroll
        for (int kk = 0; kk < 32; ++kk) {
            const float4 a4 = *(const float4*)&Asf[kk][ty * 4];
            const float4 b4 = *(const float4*)&Wsf[kk][tx * 4];
            acc[0][0] += a4.x * b4.x; acc[0][1] += a4.x * b4.y;
            acc[0][2] += a4.x * b4.z; acc[0][3] += a4.x * b4.w;
            acc[1][0] += a4.y * b4.x; acc[1][1] += a4.y * b4.y;
            acc[1][2] += a4.y * b4.z; acc[1][3] += a4.y * b4.w;
            acc[2][0] += a4.z * b4.x; acc[2][1] += a4.z * b4.y;
            acc[2][2] += a4.z * b4.z; acc[2][3] += a4.z * b4.w;
            acc[3][0] += a4.w * b4.x; acc[3][1] += a4.w * b4.y;
            acc[3][2] += a4.w * b4.z; acc[3][3] += a4.w * b4.w;
        }
    }
#pragma unroll
    for (int i = 0; i < 4; ++i) {
        float4 v = make_float4(acc[i][0], acc[i][1], acc[i][2], acc[i][3]);
        *(float4*)&part[((size_t)ks * 12800 + rowbase + ty * 4 + i) * 64 + tx * 4] = v;
    }
}

// ---------------------------------------------------------------------------
extern "C" void kernel_launch(void* const* d_in, const int* in_sizes, int n_in,
                              void* d_out, int out_size, void* d_ws, size_t ws_size,
                              hipStream_t stream)
{
    const float* x  = (const float*)d_in[0];
    const float* W1 = (const float*)d_in[1];
    const float* b1 = (const float*)d_in[2];
    const float* W2 = (const float*)d_in[3];
    const float* b2 = (const float*)d_in[4];
    const float* W3 = (const float*)d_in[5];
    const float* b3 = (const float*)d_in[6];

    char* ws = (char*)d_ws;

    const size_t oW1p  = 0;              //  18,874,368
    const size_t oW2p  = 18874368;       //  50,331,648
    const size_t oW3p  = 69206016;       //     786,432
    const size_t oXi8  = 69992448;       //  19,660,800
    const size_t oS1   = 89653248;       //   1,048,576
    const size_t oS2   = 90701824;       //  52,428,800
    const size_t oM1   = 143130624;      //   4,194,304
    const size_t oM2   = 147324928;      //   4,194,304
    const size_t oPart = 151519232;      //  33,554,432 (z=6 uses 24 MB; part3 aliases)
    const size_t oCur1 = 185073664;      // 104,857,600
    const size_t NEED  = 289931264;

    const double bnd1 = 1.0 / sqrt(1536.0);
    const double bnd2 = 1.0 / 64.0;
    const double bnd3 = 1.0 / 64.0;
    const float inv1 = (float)((double)DEN / bnd1), sb1 = (float)(bnd1 / (double)DEN);
    const float inv2 = (float)((double)DEN / bnd2), sb2 = (float)(bnd2 / (double)DEN);
    const float inv3 = (float)((double)DEN / bnd3), sb3 = (float)(bnd3 / (double)DEN);

    if (ws_size >= NEED) {
        char*  W1p  = ws + oW1p;
        char*  W2p  = ws + oW2p;
        char*  W3p  = ws + oW3p;
        char*  xi8  = ws + oXi8;
        char*  s1   = ws + oS1;
        char*  s2   = ws + oS2;
        float* m1   = (float*)(ws + oM1);
        float* m2   = (float*)(ws + oM2);
        float* part = (float*)(ws + oPart);
        float* cur1 = (float*)(ws + oCur1);
        float* part3 = part;

        split3_i8<<<6144, 256, 0, stream>>>((const float4*)W1, W1p,
                                            (size_t)4096 * 1536, inv1);
        split3_i8<<<16384, 256, 0, stream>>>((const float4*)W2, W2p,
                                             (size_t)4096 * 4096, inv2);
        split3_i8<<<256, 256, 0, stream>>>((const float4*)W3, W3p,
                                           (size_t)64 * 4096, inv3);
        xcvt_i8<<<19200, 256, 0, stream>>>((const float4*)x, (uint32_t*)xi8);
        zero_ws<<<2048, 256, 0, stream>>>((float4*)m1);   // m1 + m2 contiguous

        const size_t slab = (size_t)BATCH * N_H;
        for (int chunk = 0; chunk < 2; ++chunk) {
            gemm1_full<<<1600, 256, 0, stream>>>(
                xi8 + (size_t)chunk * 25 * BATCH * 1536, W1p, cur1, sb1);
            lif1_k<<<1024, 256, 0, stream>>>(cur1, b1, m1, s1);
            for (int i = 0; i < 25; ++i) {
                const int t = chunk * 25 + i;
                gemm_i8<4096><<<384, 256, 0, stream>>>(s1, W2p, part, sb2);
                if (i < 24) {
                    fused_r2_l1<<<2048, 256, 0, stream>>>(
                        part, b2, m2, s2 + (size_t)t * slab,
                        cur1 + (size_t)(i + 1) * slab, b1, m1, s1);
                } else {
                    reduce2_k<<<1024, 256, 0, stream>>>(
                        part, b2, m2, s2 + (size_t)t * slab);
                }
            }
        }
        gemm3_i8<<<dim3(100, 6), 256, 0, stream>>>(s2, W3p, part3, sb3);
        lif3_scan<6><<<64, 256, 0, stream>>>(part3, b3, (float*)d_out);
    } else {
        float*    m1     = (float*)(ws);
        float*    m2     = (float*)(ws + (size_t)4 * 1024 * 1024);
        float*    s1f    = (float*)(ws + (size_t)8 * 1024 * 1024);
        uint32_t* s2bits = (uint32_t*)(ws + (size_t)12 * 1024 * 1024);
        float*    part   = (float*)(ws + (size_t)20 * 1024 * 1024);

        zero_ws<<<2048, 256, 0, stream>>>((float4*)m1);
        for (int t = 0; t < T_STEPS; ++t) {
            gemm_lif<1536, false><<<dim3(64, 4), 512, 0, stream>>>(
                x + (size_t)t * BATCH * 1536, W1, b1, m1, s1f, nullptr);
            gemm_lif<4096, true><<<dim3(64, 4), 512, 0, stream>>>(
                s1f, W2, b2, m2, nullptr, s2bits + (size_t)t * BATCH * 128);
        }
        gemm3_bits<<<dim3(200, 4), 256, 0, stream>>>(s2bits, W3, part);
        lif3_scan<4><<<64, 256, 0, stream>>>(part, b3, (float*)d_out);
    }
}

// Round 8
// 2071.303 us; speedup vs baseline: 1.4749x; 1.0584x over previous
//
#include <hip/hip_runtime.h>
#include <stdint.h>
#include <stddef.h>
#include <math.h>

// ContextSNN round 8: r7 + explicit LDS double-buffering (ping-pong) in all
// MFMA GEMMs: issue global_load_lds for tile k+1, compute tile k, ONE barrier
// per iteration after compute. Overlaps ~1000-cyc staging latency with MFMA.
// T=50, B=256, IN=1536, H1=H2=4096, OUT=64. LIF beta=0.9, thr=1, subtract.

#define T_STEPS 50
#define BATCH   256
#define N_H     4096
#define DEN     8355711   // 127*65536 + 127*256 + 127

typedef unsigned short u16;
typedef __attribute__((ext_vector_type(4))) int i32x4;
typedef __attribute__((ext_vector_type(4))) float f32x4;

#define GLL16(gp, lp) __builtin_amdgcn_global_load_lds( \
    (const __attribute__((address_space(1))) void*)(gp), \
    (__attribute__((address_space(3))) void*)(lp), 16, 0, 0)

// ---------------------------------------------------------------------------
// prep
// ---------------------------------------------------------------------------
__global__ __launch_bounds__(256) void zero_ws(float4* __restrict__ p) {
    p[(size_t)blockIdx.x * 256 + threadIdx.x] = make_float4(0.f, 0.f, 0.f, 0.f);
}

__device__ inline void digits3(float w, float inv_s, int& h, int& m, int& l) {
    int V = (int)rintf(w * inv_s);
    V = min(max(V, -DEN), DEN);
    l = ((V + 128) & 255) - 128;
    const int V2 = (V - l) >> 8;
    m = ((V2 + 128) & 255) - 128;
    h = (V2 - m) >> 8;
}

__global__ __launch_bounds__(256)
void split3_i8(const float4* __restrict__ W, char* __restrict__ P,
               size_t plane_elems, float inv_s)
{
    const size_t i = (size_t)blockIdx.x * 256 + threadIdx.x;
    const float4 w = W[i];
    int h0,m0,l0,h1,m1,l1,h2,m2,l2,h3,m3,l3;
    digits3(w.x, inv_s, h0, m0, l0);
    digits3(w.y, inv_s, h1, m1, l1);
    digits3(w.z, inv_s, h2, m2, l2);
    digits3(w.w, inv_s, h3, m3, l3);
    const uint32_t ph = (uint32_t)(uint8_t)h0 | ((uint32_t)(uint8_t)h1 << 8) |
                        ((uint32_t)(uint8_t)h2 << 16) | ((uint32_t)(uint8_t)h3 << 24);
    const uint32_t pm = (uint32_t)(uint8_t)m0 | ((uint32_t)(uint8_t)m1 << 8) |
                        ((uint32_t)(uint8_t)m2 << 16) | ((uint32_t)(uint8_t)m3 << 24);
    const uint32_t pl = (uint32_t)(uint8_t)l0 | ((uint32_t)(uint8_t)l1 << 8) |
                        ((uint32_t)(uint8_t)l2 << 16) | ((uint32_t)(uint8_t)l3 << 24);
    *(uint32_t*)&P[4 * i]                   = ph;
    *(uint32_t*)&P[plane_elems + 4 * i]     = pm;
    *(uint32_t*)&P[2 * plane_elems + 4 * i] = pl;
}

__global__ __launch_bounds__(256)
void xcvt_i8(const float4* __restrict__ in, uint32_t* __restrict__ out) {
    const size_t i = (size_t)blockIdx.x * 256 + threadIdx.x;
    const float4 v = in[i];
    out[i] = (uint32_t)(v.x > 0.5f) | ((uint32_t)(v.y > 0.5f) << 8) |
             ((uint32_t)(v.z > 0.5f) << 16) | ((uint32_t)(v.w > 0.5f) << 24);
}

// ---------------------------------------------------------------------------
// Layer-1 batched GEMM, double-buffered. A[6400][1536] x W1p[3][4096][1536]^T.
// 1-D grid 1600, XCD swizzle. XOR bank swizzle. Plane-fold at it=23,47,71.
// ---------------------------------------------------------------------------
__global__ __launch_bounds__(256, 2)
void gemm1_full(const char* __restrict__ A, const char* __restrict__ Wp,
                float* __restrict__ cur, float s_base)
{
    const int K = 1536, ITERS = 72;
    __shared__ char As[2 * 8192];
    __shared__ char Bs[2 * 8192];

    const int tid  = threadIdx.x;
    const int wave = tid >> 6, lane = tid & 63;
    const int wm = wave >> 1, wn = wave & 1;

    const int bid   = blockIdx.x;
    const int cbase = (((bid & 7) << 2) + ((bid >> 3) & 3)) * 128;
    const int abase = (bid >> 5) * 128;

    i32x4 acc[4][4];
    f32x4 facc[4][4];
#pragma unroll
    for (int i = 0; i < 4; ++i)
#pragma unroll
        for (int j = 0; j < 4; ++j) { acc[i][j] = (i32x4)(0); facc[i][j] = (f32x4)(0.f); }

    const int soff0 = wave * 2048 + lane * 16;
    const int soff1 = soff0 + 1024;
    const int r0 = soff0 >> 6, r1 = soff1 >> 6;
    const int kb0 = ((((soff0 >> 4) & 3) ^ ((r0 >> 1) & 3)) << 4);
    const int kb1 = ((((soff1 >> 4) & 3) ^ ((r1 >> 1) & 3)) << 4);

    const size_t aoff0 = (size_t)(abase + r0) * K + kb0;
    const size_t aoff1 = (size_t)(abase + r1) * K + kb1;
    const size_t boff0 = (size_t)(cbase + r0) * K + kb0;
    const size_t boff1 = (size_t)(cbase + r1) * K + kb1;

    const int sbase = wave * 2048;  // staging base within a buffer

    const int rlo = lane & 15, rhi = lane >> 4;
    const int qr = (rlo >> 1) & 3;
    const int rdA = (wm * 64 + rlo) * 64 + ((rhi ^ qr) << 4);
    const int rdB = (wn * 64 + rlo) * 64 + ((rhi ^ qr) << 4);

    // prologue: load tile 0 into buffer 0
    {
        const char* ak = A;
        const char* bk = Wp;
        GLL16(ak + aoff0, As + sbase);
        GLL16(ak + aoff1, As + sbase + 1024);
        GLL16(bk + boff0, Bs + sbase);
        GLL16(bk + boff1, Bs + sbase + 1024);
    }
    __syncthreads();

    for (int it = 0; it < ITERS; ++it) {
        const int buf = (it & 1) * 8192;
        if (it + 1 < ITERS) {
            const int fn = (it + 1) * 64;
            const int pn = fn / K;
            const int kn = fn - pn * K;
            const int nbuf = 8192 - buf;
            const char* ak = A + kn;
            const char* bk = Wp + (size_t)pn * ((size_t)N_H * K) + kn;
            GLL16(ak + aoff0, As + nbuf + sbase);
            GLL16(ak + aoff1, As + nbuf + sbase + 1024);
            GLL16(bk + boff0, Bs + nbuf + sbase);
            GLL16(bk + boff1, Bs + nbuf + sbase + 1024);
        }

        const char* pAf = As + buf + rdA;
        const char* pBf = Bs + buf + rdB;
        i32x4 av[4], bv[4];
#pragma unroll
        for (int i = 0; i < 4; ++i) av[i] = *(const i32x4*)(pAf + i * 1024);
#pragma unroll
        for (int j = 0; j < 4; ++j) bv[j] = *(const i32x4*)(pBf + j * 1024);
#pragma unroll
        for (int i = 0; i < 4; ++i)
#pragma unroll
            for (int j = 0; j < 4; ++j)
                acc[i][j] = __builtin_amdgcn_mfma_i32_16x16x64_i8(
                    av[i], bv[j], acc[i][j], 0, 0, 0);

        if ((((it + 1) * 64) % K) == 0) {   // plane boundary: fold exact i32 -> f32
            const int p = (it * 64) / K;
            const float sc = s_base * (float)(65536 >> (8 * p));
#pragma unroll
            for (int i = 0; i < 4; ++i)
#pragma unroll
                for (int j = 0; j < 4; ++j) {
#pragma unroll
                    for (int r = 0; r < 4; ++r)
                        facc[i][j][r] += sc * (float)acc[i][j][r];
                    acc[i][j] = (i32x4)(0);
                }
        }
        __syncthreads();
    }

    const int orow = abase + wm * 64 + rhi * 4;
    const int ocol = cbase + wn * 64 + rlo;
#pragma unroll
    for (int i = 0; i < 4; ++i)
#pragma unroll
        for (int j = 0; j < 4; ++j)
#pragma unroll
            for (int r = 0; r < 4; ++r)
                cur[(size_t)(orow + i * 16 + r) * N_H + ocol + j * 16] = facc[i][j][r];
}

// ---------------------------------------------------------------------------
// Layer-2 GEMM, double-buffered. z = plane*2 + K-half (grid 384, XCD swizzle).
// ---------------------------------------------------------------------------
template<int K>
__global__ __launch_bounds__(256, 2)
void gemm_i8(const char* __restrict__ A, const char* __restrict__ Wp,
             float* __restrict__ part, float s_base)
{
    const int ITERS = K / 128;   // 32 for K=4096
    __shared__ char As[2 * 8192];
    __shared__ char Bs[2 * 8192];

    const int tid  = threadIdx.x;
    const int wave = tid >> 6, lane = tid & 63;
    const int wm = wave >> 1, wn = wave & 1;

    const int bid   = blockIdx.x;
    const int cbase = (((bid & 7) << 2) + ((bid >> 3) & 3)) * 128;
    const int abase = ((bid >> 5) & 1) * 128;
    const int z     = bid >> 6;
    const int p = z >> 1;
    const int kstart = (z & 1) * (K / 2);

    i32x4 acc[4][4];
#pragma unroll
    for (int i = 0; i < 4; ++i)
#pragma unroll
        for (int j = 0; j < 4; ++j) acc[i][j] = (i32x4)(0);

    const int soff0 = wave * 2048 + lane * 16;
    const int soff1 = soff0 + 1024;
    const int r0 = soff0 >> 6, r1 = soff1 >> 6;
    const int kb0 = ((((soff0 >> 4) & 3) ^ ((r0 >> 1) & 3)) << 4);
    const int kb1 = ((((soff1 >> 4) & 3) ^ ((r1 >> 1) & 3)) << 4);

    const size_t aoff0 = (size_t)(abase + r0) * K + kb0;
    const size_t aoff1 = (size_t)(abase + r1) * K + kb1;
    const size_t boff0 = (size_t)(cbase + r0) * K + kb0;
    const size_t boff1 = (size_t)(cbase + r1) * K + kb1;

    const char* Bp = Wp + (size_t)p * ((size_t)N_H * K);
    const int sbase = wave * 2048;

    const int rlo = lane & 15, rhi = lane >> 4;
    const int qr = (rlo >> 1) & 3;
    const int rdA = (wm * 64 + rlo) * 64 + ((rhi ^ qr) << 4);
    const int rdB = (wn * 64 + rlo) * 64 + ((rhi ^ qr) << 4);

    {
        const char* ak = A + kstart;
        const char* bk = Bp + kstart;
        GLL16(ak + aoff0, As + sbase);
        GLL16(ak + aoff1, As + sbase + 1024);
        GLL16(bk + boff0, Bs + sbase);
        GLL16(bk + boff1, Bs + sbase + 1024);
    }
    __syncthreads();

    for (int it = 0; it < ITERS; ++it) {
        const int buf = (it & 1) * 8192;
        if (it + 1 < ITERS) {
            const int kn = kstart + (it + 1) * 64;
            const int nbuf = 8192 - buf;
            const char* ak = A + kn;
            const char* bk = Bp + kn;
            GLL16(ak + aoff0, As + nbuf + sbase);
            GLL16(ak + aoff1, As + nbuf + sbase + 1024);
            GLL16(bk + boff0, Bs + nbuf + sbase);
            GLL16(bk + boff1, Bs + nbuf + sbase + 1024);
        }

        const char* pAf = As + buf + rdA;
        const char* pBf = Bs + buf + rdB;
        i32x4 av[4], bv[4];
#pragma unroll
        for (int i = 0; i < 4; ++i) av[i] = *(const i32x4*)(pAf + i * 1024);
#pragma unroll
        for (int j = 0; j < 4; ++j) bv[j] = *(const i32x4*)(pBf + j * 1024);
#pragma unroll
        for (int i = 0; i < 4; ++i)
#pragma unroll
            for (int j = 0; j < 4; ++j)
                acc[i][j] = __builtin_amdgcn_mfma_i32_16x16x64_i8(
                    av[i], bv[j], acc[i][j], 0, 0, 0);
        __syncthreads();
    }

    const float sc = s_base * (float)(65536 >> (8 * p));
    float* pout = part + (size_t)z * (BATCH * N_H);
    const int orow = abase + wm * 64 + rhi * 4;
    const int ocol = cbase + wn * 64 + rlo;
#pragma unroll
    for (int i = 0; i < 4; ++i)
#pragma unroll
        for (int j = 0; j < 4; ++j)
#pragma unroll
            for (int r = 0; r < 4; ++r)
                pout[(size_t)(orow + i * 16 + r) * N_H + ocol + j * 16] =
                    (float)acc[i][j][r] * sc;
}

// ---------------------------------------------------------------------------
// layer-3 i8 GEMM, double-buffered
// ---------------------------------------------------------------------------
__global__ __launch_bounds__(256, 2)
void gemm3_i8(const char* __restrict__ A, const char* __restrict__ W3p,
              float* __restrict__ part3, float s_base)
{
    __shared__ char As[2 * 8192];
    __shared__ char Bs[2 * 4096];

    const int tid  = threadIdx.x;
    const int wave = tid >> 6, lane = tid & 63;
    const int wm = wave >> 1, wn = wave & 1;

    const int rowbase = blockIdx.x * 128;
    const int z = blockIdx.y;
    const int p = z >> 1;
    const int kstart = (z & 1) * 2048;

    i32x4 acc[4][2];
#pragma unroll
    for (int i = 0; i < 4; ++i)
#pragma unroll
        for (int j = 0; j < 2; ++j) acc[i][j] = (i32x4)(0);

    const int soff0 = wave * 2048 + lane * 16;
    const int soff1 = soff0 + 1024;
    const int r0 = soff0 >> 6, r1 = soff1 >> 6;
    const int kb0 = ((((soff0 >> 4) & 3) ^ ((r0 >> 1) & 3)) << 4);
    const int kb1 = ((((soff1 >> 4) & 3) ^ ((r1 >> 1) & 3)) << 4);
    const int soffB = tid * 16;
    const int rB = soffB >> 6;
    const int kbB = ((((soffB >> 4) & 3) ^ ((rB >> 1) & 3)) << 4);

    const size_t aoff0 = (size_t)(rowbase + r0) * 4096 + kb0;
    const size_t aoff1 = (size_t)(rowbase + r1) * 4096 + kb1;
    const size_t boff  = (size_t)rB * 4096 + kbB;

    const char* Bp = W3p + (size_t)p * 64 * 4096;
    const int sbase = wave * 2048;
    const int sbaseB = wave * 1024;

    const int rlo = lane & 15, rhi = lane >> 4;
    const int qr = (rlo >> 1) & 3;
    const int rdA = (wm * 64 + rlo) * 64 + ((rhi ^ qr) << 4);
    const int rdB = (wn * 32 + rlo) * 64 + ((rhi ^ qr) << 4);

    {
        GLL16(A + kstart + aoff0, As + sbase);
        GLL16(A + kstart + aoff1, As + sbase + 1024);
        GLL16(Bp + kstart + boff, Bs + sbaseB);
    }
    __syncthreads();

    for (int it = 0; it < 32; ++it) {
        const int bufA = (it & 1) * 8192;
        const int bufB = (it & 1) * 4096;
        if (it + 1 < 32) {
            const int kn = kstart + (it + 1) * 64;
            GLL16(A + kn + aoff0, As + (8192 - bufA) + sbase);
            GLL16(A + kn + aoff1, As + (8192 - bufA) + sbase + 1024);
            GLL16(Bp + kn + boff, Bs + (4096 - bufB) + sbaseB);
        }

        const char* pAf = As + bufA + rdA;
        const char* pBf = Bs + bufB + rdB;
        i32x4 av[4], bv[2];
#pragma unroll
        for (int i = 0; i < 4; ++i) av[i] = *(const i32x4*)(pAf + i * 1024);
#pragma unroll
        for (int j = 0; j < 2; ++j) bv[j] = *(const i32x4*)(pBf + j * 1024);
#pragma unroll
        for (int i = 0; i < 4; ++i)
#pragma unroll
            for (int j = 0; j < 2; ++j)
                acc[i][j] = __builtin_amdgcn_mfma_i32_16x16x64_i8(
                    av[i], bv[j], acc[i][j], 0, 0, 0);
        __syncthreads();
    }

    const float sc = s_base * (float)(65536 >> (8 * p));
    float* pout = part3 + (size_t)z * (12800 * 64);
    const int orow = rowbase + wm * 64 + rhi * 4;
    const int ocol = wn * 32 + rlo;
#pragma unroll
    for (int i = 0; i < 4; ++i)
#pragma unroll
        for (int j = 0; j < 2; ++j)
#pragma unroll
            for (int r = 0; r < 4; ++r)
                pout[(size_t)(orow + i * 16 + r) * 64 + ocol + j * 16] =
                    (float)acc[i][j][r] * sc;
}

// ---------------------------------------------------------------------------
// element-wise LIF bodies
// ---------------------------------------------------------------------------
__device__ inline void lif_elem4(float4 cur, float* __restrict__ mem,
                                 char* __restrict__ sout, size_t base)
{
    const float4 mp = *(const float4*)&mem[base];
    float4 mn;
    mn.x = 0.9f * mp.x + cur.x - ((mp.x > 1.0f) ? 1.0f : 0.0f);
    mn.y = 0.9f * mp.y + cur.y - ((mp.y > 1.0f) ? 1.0f : 0.0f);
    mn.z = 0.9f * mp.z + cur.z - ((mp.z > 1.0f) ? 1.0f : 0.0f);
    mn.w = 0.9f * mp.w + cur.w - ((mp.w > 1.0f) ? 1.0f : 0.0f);
    *(float4*)&mem[base] = mn;
    const uint32_t sp = (uint32_t)(mn.x > 1.0f) | ((uint32_t)(mn.y > 1.0f) << 8) |
                        ((uint32_t)(mn.z > 1.0f) << 16) | ((uint32_t)(mn.w > 1.0f) << 24);
    *(uint32_t*)&sout[base] = sp;
}

__global__ __launch_bounds__(256)
void lif1_k(const float* __restrict__ cur1, const float* __restrict__ b1,
            float* __restrict__ m1, char* __restrict__ s1)
{
    const int i4 = blockIdx.x * 256 + threadIdx.x;
    const size_t base = (size_t)i4 * 4;
    const int col = (int)(base & (N_H - 1));
    const float4 bv = *(const float4*)&b1[col];
    const float4 cv = *(const float4*)&cur1[base];
    float4 cur = make_float4(cv.x + bv.x, cv.y + bv.y, cv.z + bv.z, cv.w + bv.w);
    lif_elem4(cur, m1, s1, base);
}

__global__ __launch_bounds__(256)
void reduce2_k(const float* __restrict__ part, const float* __restrict__ b2,
               float* __restrict__ m2, char* __restrict__ s2)
{
    const int i4 = blockIdx.x * 256 + threadIdx.x;
    const size_t base = (size_t)i4 * 4;
    const int col = (int)(base & (N_H - 1));
    float4 cur = *(const float4*)&b2[col];
#pragma unroll
    for (int g = 0; g < 6; ++g) {
        const float4 pv = *(const float4*)&part[(size_t)g * (BATCH * N_H) + base];
        cur.x += pv.x; cur.y += pv.y; cur.z += pv.z; cur.w += pv.w;
    }
    lif_elem4(cur, m2, s2, base);
}

__global__ __launch_bounds__(256)
void fused_r2_l1(const float* __restrict__ part, const float* __restrict__ b2,
                 float* __restrict__ m2, char* __restrict__ s2,
                 const float* __restrict__ cur1, const float* __restrict__ b1,
                 float* __restrict__ m1, char* __restrict__ s1)
{
    if (blockIdx.x < 1024) {
        const int i4 = blockIdx.x * 256 + threadIdx.x;
        const size_t base = (size_t)i4 * 4;
        const int col = (int)(base & (N_H - 1));
        float4 cur = *(const float4*)&b2[col];
#pragma unroll
        for (int g = 0; g < 6; ++g) {
            const float4 pv = *(const float4*)&part[(size_t)g * (BATCH * N_H) + base];
            cur.x += pv.x; cur.y += pv.y; cur.z += pv.z; cur.w += pv.w;
        }
        lif_elem4(cur, m2, s2, base);
    } else {
        const int i4 = (blockIdx.x - 1024) * 256 + threadIdx.x;
        const size_t base = (size_t)i4 * 4;
        const int col = (int)(base & (N_H - 1));
        const float4 bv = *(const float4*)&b1[col];
        const float4 cv = *(const float4*)&cur1[base];
        float4 cur = make_float4(cv.x + bv.x, cv.y + bv.y, cv.z + bv.z, cv.w + bv.w);
        lif_elem4(cur, m1, s1, base);
    }
}

template<int NG>
__global__ __launch_bounds__(256)
void lif3_scan(const float* __restrict__ part, const float* __restrict__ b3,
               float* __restrict__ out)
{
    const int g = blockIdx.x * 256 + threadIdx.x;
    const int j = g & 63;
    const int b = g >> 6;
    const float bj = b3[j];
    float m = 0.f, accum = 0.f;
    for (int t = 0; t < T_STEPS; ++t) {
        const size_t row = (size_t)t * 256 + b;
        float cur = bj;
#pragma unroll
        for (int q = 0; q < NG; ++q)
            cur += part[(size_t)q * (12800 * 64) + row * 64 + j];
        const float reset = (m > 1.0f) ? 1.0f : 0.0f;
        m = 0.9f * m + cur - reset;
        accum += (m > 1.0f) ? 1.0f : 0.0f;
    }
    out[g] = accum;
}

// ---------------------------------------------------------------------------
// fp32 fallback path (round 1) — used only if ws_size too small
// ---------------------------------------------------------------------------
template<int K, bool PACK_BITS>
__global__ __launch_bounds__(512)
void gemm_lif(const float* __restrict__ A, const float* __restrict__ W,
              const float* __restrict__ bias, float* __restrict__ mem,
              float* __restrict__ s_f32, uint32_t* __restrict__ s_bits)
{
    __shared__ float Asf[32][68];
    __shared__ float Wsf[32][68];
    __shared__ uint8_t us[64][64];

    const int tid = threadIdx.x;
    const int abase = blockIdx.y * 64;
    const int cbase = blockIdx.x * 64;
    const int tx = tid & 15;
    const int ty = tid >> 4;

    float acc[2][4];
#pragma unroll
    for (int i = 0; i < 2; ++i)
#pragma unroll
        for (int j = 0; j < 4; ++j) acc[i][j] = 0.f;

    const int lrow = tid >> 3;
    const int lg = tid & 7;

    for (int k0 = 0; k0 < K; k0 += 32) {
        const float4 av = *(const float4*)&A[(size_t)(abase + lrow) * K + k0 + lg * 4];
        const float4 wv = *(const float4*)&W[(size_t)(cbase + lrow) * K + k0 + lg * 4];
        __syncthreads();
        Asf[lg * 4 + 0][lrow] = av.x; Asf[lg * 4 + 1][lrow] = av.y;
        Asf[lg * 4 + 2][lrow] = av.z; Asf[lg * 4 + 3][lrow] = av.w;
        Wsf[lg * 4 + 0][lrow] = wv.x; Wsf[lg * 4 + 1][lrow] = wv.y;
        Wsf[lg * 4 + 2][lrow] = wv.z; Wsf[lg * 4 + 3][lrow] = wv.w;
        __syncthreads();
#pragma unroll
        for (int kk = 0; kk < 32; ++kk) {
            const float2 a2 = *(const float2*)&Asf[kk][ty * 2];
            const float4 b4 = *(const float4*)&Wsf[kk][tx * 4];
            acc[0][0] += a2.x * b4.x; acc[0][1] += a2.x * b4.y;
            acc[0][2] += a2.x * b4.z; acc[0][3] += a2.x * b4.w;
            acc[1][0] += a2.y * b4.x; acc[1][1] += a2.y * b4.y;
            acc[1][2] += a2.y * b4.z; acc[1][3] += a2.y * b4.w;
        }
    }

    const int r0 = abase + ty * 2;
    const int c0loc = tx * 4;
    const int c0 = cbase + c0loc;
    const float4 bv = *(const float4*)&bias[c0];

#pragma unroll
    for (int i = 0; i < 2; ++i) {
        const size_t off = (size_t)(r0 + i) * N_H + c0;
        const float4 mp = *(const float4*)&mem[off];
        float4 mn, sp;
        { float cur = acc[i][0] + bv.x;
          mn.x = 0.9f * mp.x + cur - ((mp.x > 1.0f) ? 1.0f : 0.0f);
          sp.x = (mn.x > 1.0f) ? 1.0f : 0.0f; }
        { float cur = acc[i][1] + bv.y;
          mn.y = 0.9f * mp.y + cur - ((mp.y > 1.0f) ? 1.0f : 0.0f);
          sp.y = (mn.y > 1.0f) ? 1.0f : 0.0f; }
        { float cur = acc[i][2] + bv.z;
          mn.z = 0.9f * mp.z + cur - ((mp.z > 1.0f) ? 1.0f : 0.0f);
          sp.z = (mn.z > 1.0f) ? 1.0f : 0.0f; }
        { float cur = acc[i][3] + bv.w;
          mn.w = 0.9f * mp.w + cur - ((mp.w > 1.0f) ? 1.0f : 0.0f);
          sp.w = (mn.w > 1.0f) ? 1.0f : 0.0f; }
        *(float4*)&mem[off] = mn;
        if constexpr (!PACK_BITS) {
            *(float4*)&s_f32[off] = sp;
        } else {
            us[ty * 2 + i][c0loc + 0] = (uint8_t)sp.x;
            us[ty * 2 + i][c0loc + 1] = (uint8_t)sp.y;
            us[ty * 2 + i][c0loc + 2] = (uint8_t)sp.z;
            us[ty * 2 + i][c0loc + 3] = (uint8_t)sp.w;
        }
    }

    if constexpr (PACK_BITS) {
        __syncthreads();
        if (tid < 128) {
            const int r = tid >> 1;
            const int w = tid & 1;
            uint32_t bits = 0;
#pragma unroll
            for (int b = 0; b < 32; ++b)
                bits |= ((uint32_t)us[r][w * 32 + b]) << b;
            s_bits[(size_t)(abase + r) * 128 + (cbase >> 5) + w] = bits;
        }
    }
}

__global__ __launch_bounds__(256)
void gemm3_bits(const uint32_t* __restrict__ s_bits, const float* __restrict__ W3,
                float* __restrict__ part)
{
    __shared__ float Asf[32][68];
    __shared__ float Wsf[32][68];

    const int tid = threadIdx.x;
    const int rowbase = blockIdx.x * 64;
    const int ks = blockIdx.y;
    const int tx = tid & 15;
    const int ty = tid >> 4;

    float acc[4][4];
#pragma unroll
    for (int i = 0; i < 4; ++i)
#pragma unroll
        for (int j = 0; j < 4; ++j) acc[i][j] = 0.f;

    const int r  = tid & 63;
    const int q  = tid >> 6;
    const int wr = tid >> 3;
    const int wg = tid & 7;

    for (int c = 0; c < 32; ++c) {
        const int k0 = ks * 1024 + c * 32;
        const uint32_t word = s_bits[(size_t)(rowbase + r) * 128 + (k0 >> 5)];
        const float4 wv0 = *(const float4*)&W3[(size_t)wr * 4096 + k0 + wg * 4];
        const float4 wv1 = *(const float4*)&W3[(size_t)(wr + 32) * 4096 + k0 + wg * 4];
        __syncthreads();
#pragma unroll
        for (int u = 0; u < 8; ++u)
            Asf[q * 8 + u][r] = (float)((word >> (q * 8 + u)) & 1u);
        Wsf[wg * 4 + 0][wr] = wv0.x;
        Wsf[wg * 4 + 1][wr] = wv0.y;
        Wsf[wg * 4 + 2][wr] = wv0.z;
        Wsf[wg * 4 + 3][wr] = wv0.w;
        Wsf[wg * 4 + 0][wr + 32] = wv1.x;
        Wsf[wg * 4 + 1][wr + 32] = wv1.y;
        Wsf[wg * 4 + 2][wr + 32] = wv1.z;
        Wsf[wg * 4 + 3][wr + 32] = wv1.w;
        __syncthreads();
#pragma unroll
        for (int kk = 0; kk < 32; ++kk) {
            const float4 a4 = *(const float4*)&Asf[kk][ty * 4];
            const float4 b4 = *(const float4*)&Wsf[kk][tx * 4];
            acc[0][0] += a4.x * b4.x; acc[0][1] += a4.x * b4.y;
            acc[0][2] += a4.x * b4.z; acc[0][3] += a4.x * b4.w;
            acc[1][0] += a4.y * b4.x; acc[1][1] += a4.y * b4.y;
            acc[1][2] += a4.y * b4.z; acc[1][3] += a4.y * b4.w;
            acc[2][0] += a4.z * b4.x; acc[2][1] += a4.z * b4.y;
            acc[2][2] += a4.z * b4.z; acc[2][3] += a4.z * b4.w;
            acc[3][0] += a4.w * b4.x; acc[3][1] += a4.w * b4.y;
            acc[3][2] += a4.w * b4.z; acc[3][3] += a4.w * b4.w;
        }
    }
#pragma unroll
    for (int i = 0; i < 4; ++i) {
        float4 v = make_float4(acc[i][0], acc[i][1], acc[i][2], acc[i][3]);
        *(float4*)&part[((size_t)ks * 12800 + rowbase + ty * 4 + i) * 64 + tx * 4] = v;
    }
}

// ---------------------------------------------------------------------------
extern "C" void kernel_launch(void* const* d_in, const int* in_sizes, int n_in,
                              void* d_out, int out_size, void* d_ws, size_t ws_size,
                              hipStream_t stream)
{
    const float* x  = (const float*)d_in[0];
    const float* W1 = (const float*)d_in[1];
    const float* b1 = (const float*)d_in[2];
    const float* W2 = (const float*)d_in[3];
    const float* b2 = (const float*)d_in[4];
    const float* W3 = (const float*)d_in[5];
    const float* b3 = (const float*)d_in[6];

    char* ws = (char*)d_ws;

    const size_t oW1p  = 0;              //  18,874,368
    const size_t oW2p  = 18874368;       //  50,331,648
    const size_t oW3p  = 69206016;       //     786,432
    const size_t oXi8  = 69992448;       //  19,660,800
    const size_t oS1   = 89653248;       //   1,048,576
    const size_t oS2   = 90701824;       //  52,428,800
    const size_t oM1   = 143130624;      //   4,194,304
    const size_t oM2   = 147324928;      //   4,194,304
    const size_t oPart = 151519232;      //  33,554,432
    const size_t oCur1 = 185073664;      // 104,857,600
    const size_t NEED  = 289931264;

    const double bnd1 = 1.0 / sqrt(1536.0);
    const double bnd2 = 1.0 / 64.0;
    const double bnd3 = 1.0 / 64.0;
    const float inv1 = (float)((double)DEN / bnd1), sb1 = (float)(bnd1 / (double)DEN);
    const float inv2 = (float)((double)DEN / bnd2), sb2 = (float)(bnd2 / (double)DEN);
    const float inv3 = (float)((double)DEN / bnd3), sb3 = (float)(bnd3 / (double)DEN);

    if (ws_size >= NEED) {
        char*  W1p  = ws + oW1p;
        char*  W2p  = ws + oW2p;
        char*  W3p  = ws + oW3p;
        char*  xi8  = ws + oXi8;
        char*  s1   = ws + oS1;
        char*  s2   = ws + oS2;
        float* m1   = (float*)(ws + oM1);
        float* m2   = (float*)(ws + oM2);
        float* part = (float*)(ws + oPart);
        float* cur1 = (float*)(ws + oCur1);
        float* part3 = part;

        split3_i8<<<6144, 256, 0, stream>>>((const float4*)W1, W1p,
                                            (size_t)4096 * 1536, inv1);
        split3_i8<<<16384, 256, 0, stream>>>((const float4*)W2, W2p,
                                             (size_t)4096 * 4096, inv2);
        split3_i8<<<256, 256, 0, stream>>>((const float4*)W3, W3p,
                                           (size_t)64 * 4096, inv3);
        xcvt_i8<<<19200, 256, 0, stream>>>((const float4*)x, (uint32_t*)xi8);
        zero_ws<<<2048, 256, 0, stream>>>((float4*)m1);   // m1 + m2 contiguous

        const size_t slab = (size_t)BATCH * N_H;
        for (int chunk = 0; chunk < 2; ++chunk) {
            gemm1_full<<<1600, 256, 0, stream>>>(
                xi8 + (size_t)chunk * 25 * BATCH * 1536, W1p, cur1, sb1);
            lif1_k<<<1024, 256, 0, stream>>>(cur1, b1, m1, s1);
            for (int i = 0; i < 25; ++i) {
                const int t = chunk * 25 + i;
                gemm_i8<4096><<<384, 256, 0, stream>>>(s1, W2p, part, sb2);
                if (i < 24) {
                    fused_r2_l1<<<2048, 256, 0, stream>>>(
                        part, b2, m2, s2 + (size_t)t * slab,
                        cur1 + (size_t)(i + 1) * slab, b1, m1, s1);
                } else {
                    reduce2_k<<<1024, 256, 0, stream>>>(
                        part, b2, m2, s2 + (size_t)t * slab);
                }
            }
        }
        gemm3_i8<<<dim3(100, 6), 256, 0, stream>>>(s2, W3p, part3, sb3);
        lif3_scan<6><<<64, 256, 0, stream>>>(part3, b3, (float*)d_out);
    } else {
        float*    m1     = (float*)(ws);
        float*    m2     = (float*)(ws + (size_t)4 * 1024 * 1024);
        float*    s1f    = (float*)(ws + (size_t)8 * 1024 * 1024);
        uint32_t* s2bits = (uint32_t*)(ws + (size_t)12 * 1024 * 1024);
        float*    part   = (float*)(ws + (size_t)20 * 1024 * 1024);

        zero_ws<<<2048, 256, 0, stream>>>((float4*)m1);
        for (int t = 0; t < T_STEPS; ++t) {
            gemm_lif<1536, false><<<dim3(64, 4), 512, 0, stream>>>(
                x + (size_t)t * BATCH * 1536, W1, b1, m1, s1f, nullptr);
            gemm_lif<4096, true><<<dim3(64, 4), 512, 0, stream>>>(
                s1f, W2, b2, m2, nullptr, s2bits + (size_t)t * BATCH * 128);
        }
        gemm3_bits<<<dim3(200, 4), 256, 0, stream>>>(s2bits, W3, part);
        lif3_scan<4><<<64, 256, 0, stream>>>(part, b3, (float*)d_out);
    }
}